// Round 12
// baseline (423.518 us; speedup 1.0000x reference)
//
#include <hip/hip_runtime.h>

#define BATCH 32
#define NPT   1024
#define CC    14
#define KNN   9
#define EDIM  128
#define HDIM  128
#define NCLS  25
#define BN    (BATCH*NPT)

#define RSTR  132     // radF row stride (ushort): 66 dw -> start bank 2*r (distinct)
#define SSTR  140     // sil row stride (ushort): 70 dw -> start bank 6*r (distinct)

typedef float  v4f __attribute__((ext_vector_type(4)));
typedef __bf16 v8bf __attribute__((ext_vector_type(8)));

// symmetric-pair enumeration (c<=e) of the 14x14 radial matrix: 105 entries
__device__ const unsigned char PC_tab[105] = {
    0,0,0,0,0,0,0,0,0,0,0,0,0,0,
    1,1,1,1,1,1,1,1,1,1,1,1,1,
    2,2,2,2,2,2,2,2,2,2,2,2,
    3,3,3,3,3,3,3,3,3,3,3,
    4,4,4,4,4,4,4,4,4,4,
    5,5,5,5,5,5,5,5,5,
    6,6,6,6,6,6,6,6,
    7,7,7,7,7,7,7,
    8,8,8,8,8,8,
    9,9,9,9,9,
    10,10,10,10,
    11,11,11,
    12,12,
    13};
__device__ const unsigned char PE_tab[105] = {
    0,1,2,3,4,5,6,7,8,9,10,11,12,13,
    1,2,3,4,5,6,7,8,9,10,11,12,13,
    2,3,4,5,6,7,8,9,10,11,12,13,
    3,4,5,6,7,8,9,10,11,12,13,
    4,5,6,7,8,9,10,11,12,13,
    5,6,7,8,9,10,11,12,13,
    6,7,8,9,10,11,12,13,
    7,8,9,10,11,12,13,
    8,9,10,11,12,13,
    9,10,11,12,13,
    10,11,12,13,
    11,12,13,
    12,13,
    13};

__device__ __forceinline__ float silu_f(float x) {
    const float e = __expf(-x);
    return x * __builtin_amdgcn_rcpf(1.0f + e);
}
__device__ __forceinline__ float sigm_f(float x) {
    const float e = __expf(-x);
    return __builtin_amdgcn_rcpf(1.0f + e);
}

__device__ __forceinline__ unsigned short f2bf_rne(float f) {
    union { float f; unsigned u; } v; v.f = f;
    unsigned r = v.u + 0x7fffu + ((v.u >> 16) & 1u);
    return (unsigned short)(r >> 16);
}
__device__ __forceinline__ unsigned short f2bf(float f) {
    union { float f; unsigned u; } v; v.f = f;
    return (unsigned short)((v.u + 0x8000u) >> 16);
}

// ---------------- K0: weight prep (transpose + bf16 + symmetric fold) ----------------
__global__ __launch_bounds__(256) void k_prep(
    const float* __restrict__ We1, const float* __restrict__ We2,
    const float* __restrict__ Wx1, const float* __restrict__ Wh1,
    const float* __restrict__ Wh2, const float* __restrict__ Wd1,
    const float* __restrict__ Wp1, const float* __restrict__ Wr1,
    const float* __restrict__ Wt1, const float* __restrict__ Wt2,
    const float* __restrict__ Wr2,
    unsigned short* __restrict__ WeF,  unsigned short* __restrict__ We2t,
    unsigned short* __restrict__ Wx1t, unsigned short* __restrict__ Wh1t,
    unsigned short* __restrict__ Wh2t, unsigned short* __restrict__ Wd1t,
    unsigned short* __restrict__ Wp1t, unsigned short* __restrict__ Wr1t,
    unsigned short* __restrict__ Wt1t, unsigned short* __restrict__ Wt2t,
    unsigned short* __restrict__ We1Ft, unsigned short* __restrict__ Wr2t)
{
    int i = blockIdx.x * 256 + threadIdx.x;
    if (i < 16384) {   // folded symmetric radial weights: [ch][k<=127], K=105 real
        const int ch = i >> 7, k = i & 127;
        float v = 0.0f;
        if (k < 105) {
            const int c = PC_tab[k], e = PE_tab[k];
            v = We1[(size_t)(256 + c*14 + e)*128 + ch];
            if (c != e) v += We1[(size_t)(256 + e*14 + c)*128 + ch];
        }
        WeF[i] = f2bf_rne(v);
        return;
    }
    i -= 16384;
    if (i < 16384) { We2t[i] = f2bf_rne(We2[(size_t)(i % 128)*128 + i/128]); return; }
    i -= 16384;
    if (i < 16384) { Wx1t[i] = f2bf_rne(Wx1[(size_t)(i % 128)*128 + i/128]); return; }
    i -= 16384;
    if (i < 32768) { const int c = i/256, k = i%256; Wh1t[i] = f2bf_rne(Wh1[(size_t)k*128 + c]); return; }
    i -= 32768;
    if (i < 16384) { Wh2t[i] = f2bf_rne(Wh2[(size_t)(i % 128)*128 + i/128]); return; }
    i -= 16384;
    if (i < 32768) {
        const int t = i/128, k = i%128;
        Wd1t[i] = f2bf_rne((t < 128) ? Wd1[(size_t)k*128 + t] : Wd1[(size_t)(128 + k)*128 + (t - 128)]);
        return;
    }
    i -= 32768;
    if (i < 16384) { Wp1t[i] = f2bf_rne(Wp1[(size_t)(i % 128)*128 + i/128]); return; }
    i -= 16384;
    if (i < 16384) { Wr1t[i] = f2bf_rne(Wr1[(size_t)(i % 128)*128 + i/128]); return; }
    i -= 16384;
    if (i < 16384) { Wt1t[i] = f2bf_rne(Wt1[(size_t)(i % 128)*128 + i/128]); return; }
    i -= 16384;
    if (i < 16384) { Wt2t[i] = f2bf_rne(Wt2[(size_t)(i % 128)*128 + i/128]); return; }
    i -= 16384;
    if (i < 32768) {
        const float* q = (i/128 < 128) ? &We1[(size_t)(i%128)*128 + i/128]
                                       : &We1[(size_t)(128 + i%128)*128 + (i/128 - 128)];
        We1Ft[i] = f2bf_rne(*q);
        return;
    }
    i -= 32768;
    if (i < 4096) {    // logits weight: [ch 0..31][k 0..127], ch>=25 zero
        const int ch = i >> 7, k = i & 127;
        Wr2t[i] = (ch < NCLS) ? f2bf_rne(Wr2[(size_t)k*NCLS + ch]) : (unsigned short)0;
    }
}

// ---------------- K1: FUSED hhP (blocks 0..1023) + knn (blocks 1024..1535) ----------------
__global__ __launch_bounds__(256) void k_hhPknn(
    const float* __restrict__ t, const int* __restrict__ S,
    const float* __restrict__ emb,
    const unsigned short* __restrict__ Wt1t, const float* __restrict__ bt1,
    const unsigned short* __restrict__ Wt2t, const float* __restrict__ bt2,
    const unsigned short* __restrict__ We1Ft, const float* __restrict__ be1,
    float* __restrict__ Hh, float* __restrict__ P,
    const float* __restrict__ X, int* __restrict__ idxb)
{
    __shared__ __align__(16) unsigned char smem[34816];
    const int tid = threadIdx.x;

    if (blockIdx.x < BN/32) {
        // ================= hhP =================
        unsigned short* A0 = (unsigned short*)smem;
        unsigned short* A1 = A0 + 32*140;
        unsigned short* A2 = A1 + 32*140;
        int*            sInt = (int*)(A2 + 32*140);

        const int wv   = tid >> 6, lane = tid & 63;
        const int quad = lane >> 4, r16 = lane & 15;
        const int col  = tid & 127, rh = tid >> 7;
        const int base = blockIdx.x * 32;

        if (tid < 32) sInt[tid] = S[base + tid];

        const float step  = 1.0f / 127.0f;
        const float coeff = -0.5f / (step * step);
        const float off   = step * (float)col;
        #pragma unroll
        for (int rr = 0; rr < 16; ++rr) {
            const int r = rh*16 + rr;
            const float d = t[base + r] - off + 1e-6f;
            A0[r*140 + col] = f2bf(__expf(coeff * d * d));
        }
        __syncthreads();

        // MM_t1
        {
            v8bf a[2][4];
            #pragma unroll
            for (int g = 0; g < 2; ++g)
                #pragma unroll
                for (int ks = 0; ks < 4; ++ks)
                    a[g][ks] = *(const v8bf*)(A0 + (16*g + r16)*140 + ks*32 + quad*8);
            #pragma unroll
            for (int c2 = 0; c2 < 2; ++c2) {
                const int ch = (wv*2 + c2)*16 + r16;
                v4f acc[2] = {(v4f){0,0,0,0}, (v4f){0,0,0,0}};
                #pragma unroll
                for (int ks = 0; ks < 4; ++ks) {
                    const v8bf bb = *(const v8bf*)(Wt1t + (size_t)ch*128 + ks*32 + quad*8);
                    acc[0] = __builtin_amdgcn_mfma_f32_16x16x32_bf16(a[0][ks], bb, acc[0], 0, 0, 0);
                    acc[1] = __builtin_amdgcn_mfma_f32_16x16x32_bf16(a[1][ks], bb, acc[1], 0, 0, 0);
                }
                const float bc = bt1[ch];
                #pragma unroll
                for (int g = 0; g < 2; ++g)
                    #pragma unroll
                    for (int rr = 0; rr < 4; ++rr)
                        A1[(16*g + quad*4 + rr)*140 + ch] = f2bf(fmaxf(acc[g][rr] + bc, 0.0f));
            }
        }
        __syncthreads();

        // MM_t2
        {
            v8bf a[2][4];
            #pragma unroll
            for (int g = 0; g < 2; ++g)
                #pragma unroll
                for (int ks = 0; ks < 4; ++ks)
                    a[g][ks] = *(const v8bf*)(A1 + (16*g + r16)*140 + ks*32 + quad*8);
            #pragma unroll
            for (int c2 = 0; c2 < 2; ++c2) {
                const int ch = (wv*2 + c2)*16 + r16;
                v4f acc[2] = {(v4f){0,0,0,0}, (v4f){0,0,0,0}};
                #pragma unroll
                for (int ks = 0; ks < 4; ++ks) {
                    const v8bf bb = *(const v8bf*)(Wt2t + (size_t)ch*128 + ks*32 + quad*8);
                    acc[0] = __builtin_amdgcn_mfma_f32_16x16x32_bf16(a[0][ks], bb, acc[0], 0, 0, 0);
                    acc[1] = __builtin_amdgcn_mfma_f32_16x16x32_bf16(a[1][ks], bb, acc[1], 0, 0, 0);
                }
                const float bc = bt2[ch];
                #pragma unroll
                for (int g = 0; g < 2; ++g)
                    #pragma unroll
                    for (int rr = 0; rr < 4; ++rr) {
                        const int row = 16*g + quad*4 + rr;
                        const int node = base + row;
                        const float hh = emb[sInt[row]*128 + ch] + acc[g][rr] + bc;
                        Hh[(size_t)node*128 + ch] = hh;
                        A2[row*140 + ch] = f2bf(silu_f(hh));
                    }
            }
        }
        __syncthreads();

        // MM_P
        {
            v8bf a[2][4];
            #pragma unroll
            for (int g = 0; g < 2; ++g)
                #pragma unroll
                for (int ks = 0; ks < 4; ++ks)
                    a[g][ks] = *(const v8bf*)(A2 + (16*g + r16)*140 + ks*32 + quad*8);
            #pragma unroll
            for (int c2 = 0; c2 < 4; ++c2) {
                const int ch = (wv*4 + c2)*16 + r16;
                v4f acc[2] = {(v4f){0,0,0,0}, (v4f){0,0,0,0}};
                #pragma unroll
                for (int ks = 0; ks < 4; ++ks) {
                    const v8bf bb = *(const v8bf*)(We1Ft + (size_t)ch*128 + ks*32 + quad*8);
                    acc[0] = __builtin_amdgcn_mfma_f32_16x16x32_bf16(a[0][ks], bb, acc[0], 0, 0, 0);
                    acc[1] = __builtin_amdgcn_mfma_f32_16x16x32_bf16(a[1][ks], bb, acc[1], 0, 0, 0);
                }
                const float fb = (ch < 128) ? be1[ch] : 0.0f;
                #pragma unroll
                for (int g = 0; g < 2; ++g)
                    #pragma unroll
                    for (int rr = 0; rr < 4; ++rr)
                        P[(size_t)(base + 16*g + quad*4 + rr)*256 + ch] = acc[g][rr] + fb;
            }
        }
        return;
    }

    // ================= knn =================
    {
        float4* Cc   = (float4*)smem;
        float*  dshp = (float*)(smem + 16384);
        int*    ishp = (int*)  (smem + 25600);

        const int kb = blockIdx.x - BN/32;
        const int lane = tid & 63, wv = tid >> 6;
        const int bb = kb >> 4;
        const int n0 = (kb & 15) << 6;
        const float* Xb = X + (size_t)bb * NPT * 42;

        for (int i = tid; i < NPT; i += 256) {
            const float* p = Xb + (size_t)i*42 + 3;
            Cc[i] = make_float4(p[0], p[1], p[2], 0.0f);
        }
        __syncthreads();

        const int n = n0 + lane;
        const float4 c = Cc[n];

        float dist[KNN]; int ind[KNN];
        #pragma unroll
        for (int k = 0; k < KNN; ++k) { dist[k] = 3.0e38f; ind[k] = -1; }

        const int j0 = wv * 256;
        for (int jj = 0; jj < 256; ++jj) {
            const int j = j0 + jj;
            const float4 q = Cc[j];
            const float dx = __fsub_rn(c.x, q.x);
            const float dy = __fsub_rn(c.y, q.y);
            const float dz = __fsub_rn(c.z, q.z);
            float d = __fadd_rn(__fadd_rn(__fmul_rn(dx,dx), __fmul_rn(dy,dy)), __fmul_rn(dz,dz));
            if (j == n) d = __fadd_rn(d, 1e10f);
            if (d < dist[KNN-1]) {
                dist[KNN-1] = d; ind[KNN-1] = j;
                #pragma unroll
                for (int p = KNN-1; p > 0; --p) {
                    if (dist[p] < dist[p-1]) {
                        float td = dist[p]; dist[p] = dist[p-1]; dist[p-1] = td;
                        int   ti = ind[p];  ind[p]  = ind[p-1];  ind[p-1]  = ti;
                    }
                }
            }
        }
        #pragma unroll
        for (int k = 0; k < KNN; ++k) {
            dshp[((wv*64 + lane))*KNN + k] = dist[k];
            ishp[((wv*64 + lane))*KNN + k] = ind[k];
        }
        __syncthreads();

        if (tid < 64) {
            float fd[KNN]; int fi[KNN];
            #pragma unroll
            for (int k = 0; k < KNN; ++k) { fd[k] = 3.0e38f; fi[k] = -1; }
            for (int w = 0; w < 4; ++w)
                #pragma unroll
                for (int k = 0; k < KNN; ++k) {
                    const float d = dshp[(w*64 + tid)*KNN + k];
                    const int   i = ishp[(w*64 + tid)*KNN + k];
                    if (d < fd[KNN-1]) {
                        fd[KNN-1] = d; fi[KNN-1] = i;
                        #pragma unroll
                        for (int p = KNN-1; p > 0; --p) {
                            if (fd[p] < fd[p-1]) {
                                float td = fd[p]; fd[p] = fd[p-1]; fd[p-1] = td;
                                int   ti = fi[p]; fi[p] = fi[p-1]; fi[p-1] = ti;
                            }
                        }
                    }
                }
            const int node = (bb << 10) + n0 + tid;
            #pragma unroll
            for (int k = 0; k < KNN; ++k) idxb[(size_t)node*KNN + k] = fi[k];
        }
    }
}

// ---------------- K4: MFMA edge pipeline, 16 nodes/block, SLOT-PAIRED ----------------
// Row = node, tile = edge-slot; 2 slots per barrier group -> 17 barriers total.
// Coordinates pre-scaled by 1/sqrt(14) so dot3 gives radial/14 directly.
__global__ __launch_bounds__(256) void k_edge(
    const float* __restrict__ X, const int* __restrict__ idxb,
    const float* __restrict__ P,
    const unsigned short* __restrict__ WeF,
    const unsigned short* __restrict__ We2t,
    const unsigned short* __restrict__ Wx1t,
    const float* __restrict__ be2,
    const float* __restrict__ bx1, const float* __restrict__ Wx2,
    const float* __restrict__ bx2,
    float* __restrict__ msum, float* __restrict__ wbuf)
{
    __shared__ unsigned short radF[2][16*RSTR];        // 8448 B
    __shared__ unsigned short silA[2][16*SSTR];        // 8960 B
    __shared__ unsigned short silB[2][16*SSTR];        // 8960 B
    __shared__ __align__(16) float relS[16][57];       // 3648 B
    __shared__ float wred[KNN][16][4];                 // 2304 B
    __shared__ int   jsh[16][KNN];                     //  576 B

    const int tid  = threadIdx.x;
    const int wv   = tid >> 6, lane = tid & 63;
    const int quad = lane >> 4, r16 = lane & 15;
    const int node0 = blockIdx.x * 16;
    const int b     = node0 >> 10;
    const int chan0 = (wv*2 + 0)*16 + r16;
    const int chan1 = (wv*2 + 1)*16 + r16;
    const int srow  = tid >> 4, c16 = tid & 15;
    const float s14 = 0.26726124f;   // 1/sqrt(14)

    if (tid < 144) jsh[tid/9][tid%9] = idxb[(size_t)(node0 + tid/9)*KNN + tid%9];

    // per-lane folded-feature pair offsets (loop-invariant), packed
    int offCE[7];
    #pragma unroll
    for (int kk = 0; kk < 7; ++kk) {
        const int f = c16 + 16*kk;
        if (f < 105) offCE[kk] = ((int)PC_tab[f]*4) | (((int)PE_tab[f]*4) << 16);
        else         offCE[kk] = 0;
    }
    // zero the K-pad (f 105..127) once, both slots
    {
        const int f6 = 96 + c16, f7 = 112 + c16;
        #pragma unroll
        for (int s = 0; s < 2; ++s) {
            if (f6 >= 105) radF[s][srow*RSTR + f6] = 0;
            radF[s][srow*RSTR + f7] = 0;
        }
    }

    // own-node coords in regs (scaled)
    float xr[3] = {0,0,0};
    if (c16 < 14) {
        #pragma unroll
        for (int k = 0; k < 3; ++k)
            xr[k] = X[(size_t)(node0 + srow)*42 + c16*3 + k] * s14;
    }

    // Pn (constant over slots)
    float pn0[4], pn1[4];
    #pragma unroll
    for (int rr = 0; rr < 4; ++rr) {
        pn0[rr] = P[(size_t)(node0 + quad*4 + rr)*256 + chan0];
        pn1[rr] = P[(size_t)(node0 + quad*4 + rr)*256 + chan1];
    }
    const float be2c0 = be2[chan0], be2c1 = be2[chan1];
    const float bxc0  = bx1[chan0], bxc1  = bx1[chan1];
    const float wxc0  = Wx2[chan0], wxc1  = Wx2[chan1];

    // B-fragments
    v8bf B1[2][4], B2[2][4], B3[2][4];
    #pragma unroll
    for (int c2 = 0; c2 < 2; ++c2) {
        const int ct = wv*2 + c2;
        #pragma unroll
        for (int ks = 0; ks < 4; ++ks) {
            B1[c2][ks] = *(const v8bf*)(WeF  + (size_t)(ct*16 + r16)*128 + ks*32 + quad*8);
            B2[c2][ks] = *(const v8bf*)(We2t + (size_t)(ct*16 + r16)*128 + ks*32 + quad*8);
            B3[c2][ks] = *(const v8bf*)(Wx1t + (size_t)(ct*16 + r16)*128 + ks*32 + quad*8);
        }
    }

    float msA0[4] = {0,0,0,0}, msA1[4] = {0,0,0,0};

    __syncthreads();   // jsh ready

    // prefetch Xj (scaled) for slots 0 and 1
    float xj[2][3] = {{0,0,0},{0,0,0}};
    if (c16 < 14) {
        #pragma unroll
        for (int s = 0; s < 2; ++s) {
            const int j = jsh[srow][s];
            #pragma unroll
            for (int k = 0; k < 3; ++k)
                xj[s][k] = X[(size_t)((b << 10) + j)*42 + c16*3 + k] * s14;
        }
    }

    for (int tp = 0; tp < KNN; tp += 2) {
        const int ns = (tp + 1 < KNN) ? 2 : 1;

        // ---- stage both slots (same-wave relS round trip; no barrier) ----
        #pragma unroll
        for (int s = 0; s < 2; ++s) {
            if (s < ns) {
                if (c16 < 14) {
                    #pragma unroll
                    for (int k = 0; k < 3; ++k)
                        relS[srow][c16*4 + k] = xr[k] - xj[s][k];
                }
                // prefetch this lane's Xj for slot tp+2+s
                if (tp + 2 + s < KNN && c16 < 14) {
                    const int j = jsh[srow][tp + 2 + s];
                    #pragma unroll
                    for (int k = 0; k < 3; ++k)
                        xj[s][k] = X[(size_t)((b << 10) + j)*42 + c16*3 + k] * s14;
                }
                const float* rb = relS[srow];
                #pragma unroll
                for (int kk = 0; kk < 7; ++kk) {
                    const int f = c16 + 16*kk;
                    if (f < 105) {
                        const int oc = offCE[kk] & 0xffff, oe = offCE[kk] >> 16;
                        const float v = rb[oc]*rb[oe] + rb[oc+1]*rb[oe+1] + rb[oc+2]*rb[oe+2];
                        radF[s][srow*RSTR + f] = f2bf(silu_f(v));
                    }
                }
            }
        }
        // prefetch pj for both slots
        float pj0[2][4], pj1[2][4];
        #pragma unroll
        for (int s = 0; s < 2; ++s)
            if (s < ns)
                #pragma unroll
                for (int rr = 0; rr < 4; ++rr) {
                    const int jq = jsh[quad*4 + rr][tp + s];
                    const size_t jrow = (size_t)((b << 10) + jq)*256 + 128;
                    pj0[s][rr] = P[jrow + chan0];
                    pj1[s][rr] = P[jrow + chan1];
                }
        __syncthreads();   // B

        // ---- layer 1 MFMA + ep1, both slots ----
        #pragma unroll
        for (int s = 0; s < 2; ++s) {
            if (s < ns) {
                v4f a0 = (v4f){0,0,0,0}, a1 = (v4f){0,0,0,0};
                #pragma unroll
                for (int ks = 0; ks < 4; ++ks) {
                    const v8bf a = *(const v8bf*)(radF[s] + r16*RSTR + ks*32 + quad*8);
                    a0 = __builtin_amdgcn_mfma_f32_16x16x32_bf16(a, B1[0][ks], a0, 0, 0, 0);
                    a1 = __builtin_amdgcn_mfma_f32_16x16x32_bf16(a, B1[1][ks], a1, 0, 0, 0);
                }
                #pragma unroll
                for (int rr = 0; rr < 4; ++rr) {
                    const int rw = quad*4 + rr;
                    silA[s][rw*SSTR + chan0] = f2bf(silu_f(a0[rr] + pn0[rr] + pj0[s][rr]));
                    silA[s][rw*SSTR + chan1] = f2bf(silu_f(a1[rr] + pn1[rr] + pj1[s][rr]));
                }
            }
        }
        __syncthreads();   // C

        // ---- layer 2 MFMA + ep2, both slots ----
        #pragma unroll
        for (int s = 0; s < 2; ++s) {
            if (s < ns) {
                v4f a0 = (v4f){0,0,0,0}, a1 = (v4f){0,0,0,0};
                #pragma unroll
                for (int ks = 0; ks < 4; ++ks) {
                    const v8bf a = *(const v8bf*)(silA[s] + r16*SSTR + ks*32 + quad*8);
                    a0 = __builtin_amdgcn_mfma_f32_16x16x32_bf16(a, B2[0][ks], a0, 0, 0, 0);
                    a1 = __builtin_amdgcn_mfma_f32_16x16x32_bf16(a, B2[1][ks], a1, 0, 0, 0);
                }
                #pragma unroll
                for (int rr = 0; rr < 4; ++rr) {
                    const float m0 = a0[rr] + be2c0;
                    const float m1 = a1[rr] + be2c1;
                    msA0[rr] += m0;  msA1[rr] += m1;
                    const int rw = quad*4 + rr;
                    silB[s][rw*SSTR + chan0] = f2bf(silu_f(m0));
                    silB[s][rw*SSTR + chan1] = f2bf(silu_f(m1));
                }
            }
        }
        __syncthreads();   // D

        // ---- layer 3 MFMA + ep3, both slots ----
        #pragma unroll
        for (int s = 0; s < 2; ++s) {
            if (s < ns) {
                v4f a0 = (v4f){0,0,0,0}, a1 = (v4f){0,0,0,0};
                #pragma unroll
                for (int ks = 0; ks < 4; ++ks) {
                    const v8bf a = *(const v8bf*)(silB[s] + r16*SSTR + ks*32 + quad*8);
                    a0 = __builtin_amdgcn_mfma_f32_16x16x32_bf16(a, B3[0][ks], a0, 0, 0, 0);
                    a1 = __builtin_amdgcn_mfma_f32_16x16x32_bf16(a, B3[1][ks], a1, 0, 0, 0);
                }
                #pragma unroll
                for (int rr = 0; rr < 4; ++rr) {
                    float pr = silu_f(a0[rr] + bxc0) * wxc0
                             + silu_f(a1[rr] + bxc1) * wxc1;
                    pr += __shfl_xor(pr, 1);
                    pr += __shfl_xor(pr, 2);
                    pr += __shfl_xor(pr, 4);
                    pr += __shfl_xor(pr, 8);
                    if (r16 == 0) wred[tp + s][quad*4 + rr][wv] = pr;
                }
            }
        }
        // next pair's radF/silA writes are fenced by barriers B/C of next iter;
        // relS is same-wave only.
    }

    #pragma unroll
    for (int rr = 0; rr < 4; ++rr) {
        msum[(size_t)(node0 + quad*4 + rr)*128 + chan0] = msA0[rr];
        msum[(size_t)(node0 + quad*4 + rr)*128 + chan1] = msA1[rr];
    }
    __syncthreads();
    if (tid < 16*KNN) {
        const int tt = tid / 16, rw = tid % 16;
        wbuf[(size_t)(node0 + rw)*KNN + tt] =
            wred[tt][rw][0] + wred[tt][rw][1] + wred[tt][rw][2] + wred[tt][rw][3] + bx2[0];
    }
}

// ---------------- K5: fused node pipeline, all-MFMA, 32 nodes/block ----------------
__global__ __launch_bounds__(256) void k_nodeF(
    const float* __restrict__ X, const float* __restrict__ Hh,
    const float* __restrict__ msum, const int* __restrict__ idxb,
    const float* __restrict__ wbuf,
    const unsigned short* __restrict__ Wh1t, const float* __restrict__ bh1,
    const unsigned short* __restrict__ Wh2t, const float* __restrict__ bh2,
    const unsigned short* __restrict__ Wd1t, const float* __restrict__ bd1,
    const int* __restrict__ S, const float* __restrict__ emb,
    const unsigned short* __restrict__ Wp1t, const float* __restrict__ bp1,
    const unsigned short* __restrict__ Wr1t, const float* __restrict__ br1,
    const unsigned short* __restrict__ Wr2t, const float* __restrict__ br2,
    float* __restrict__ Hn, float* __restrict__ AB,
    float* __restrict__ outL, float* __restrict__ outX)
{
    __shared__ __align__(16) unsigned short A0[32*268];
    __shared__ __align__(16) unsigned short A1[32*140];
    __shared__ __align__(16) unsigned short A2[32*140];
    __shared__ __align__(16) unsigned short A3[32*140];
    __shared__ int sInt[32];

    const int tid  = threadIdx.x;
    const int wv   = tid >> 6, lane = tid & 63;
    const int quad = lane >> 4, r16 = lane & 15;
    const int base = blockIdx.x * 32;

    if (tid < 32) sInt[tid] = S[base + tid];
    for (int r = 0; r < 32; ++r) {
        const int node = base + r;
        const float v = (tid < 128) ? Hh[(size_t)node*128 + tid]
                                    : msum[(size_t)node*128 + (tid - 128)];
        A0[r*268 + tid] = f2bf(silu_f(v));
    }
    __syncthreads();

    // MM1: K=256
    {
        v8bf a[2][8];
        #pragma unroll
        for (int g = 0; g < 2; ++g)
            #pragma unroll
            for (int ks = 0; ks < 8; ++ks)
                a[g][ks] = *(const v8bf*)(A0 + (16*g + r16)*268 + ks*32 + quad*8);
        #pragma unroll
        for (int c2 = 0; c2 < 2; ++c2) {
            const int ch = (wv*2 + c2)*16 + r16;
            v4f acc[2] = {(v4f){0,0,0,0}, (v4f){0,0,0,0}};
            #pragma unroll
            for (int ks = 0; ks < 8; ++ks) {
                const v8bf bb = *(const v8bf*)(Wh1t + (size_t)ch*256 + ks*32 + quad*8);
                acc[0] = __builtin_amdgcn_mfma_f32_16x16x32_bf16(a[0][ks], bb, acc[0], 0, 0, 0);
                acc[1] = __builtin_amdgcn_mfma_f32_16x16x32_bf16(a[1][ks], bb, acc[1], 0, 0, 0);
            }
            const float bc = bh1[ch];
            #pragma unroll
            for (int g = 0; g < 2; ++g)
                #pragma unroll
                for (int rr = 0; rr < 4; ++rr)
                    A1[(16*g + quad*4 + rr)*140 + ch] = f2bf(silu_f(acc[g][rr] + bc));
        }
    }
    __syncthreads();

    // MM2
    {
        v8bf a[2][4];
        #pragma unroll
        for (int g = 0; g < 2; ++g)
            #pragma unroll
            for (int ks = 0; ks < 4; ++ks)
                a[g][ks] = *(const v8bf*)(A1 + (16*g + r16)*140 + ks*32 + quad*8);
        #pragma unroll
        for (int c2 = 0; c2 < 2; ++c2) {
            const int ch = (wv*2 + c2)*16 + r16;
            v4f acc[2] = {(v4f){0,0,0,0}, (v4f){0,0,0,0}};
            #pragma unroll
            for (int ks = 0; ks < 4; ++ks) {
                const v8bf bb = *(const v8bf*)(Wh2t + (size_t)ch*128 + ks*32 + quad*8);
                acc[0] = __builtin_amdgcn_mfma_f32_16x16x32_bf16(a[0][ks], bb, acc[0], 0, 0, 0);
                acc[1] = __builtin_amdgcn_mfma_f32_16x16x32_bf16(a[1][ks], bb, acc[1], 0, 0, 0);
            }
            const float bc = bh2[ch];
            #pragma unroll
            for (int g = 0; g < 2; ++g)
                #pragma unroll
                for (int rr = 0; rr < 4; ++rr) {
                    const int row = 16*g + quad*4 + rr;
                    const int node = base + row;
                    const float hn = Hh[(size_t)node*128 + ch] + acc[g][rr] + bc;
                    Hn[(size_t)node*128 + ch] = hn;
                    A2[row*140 + ch] = f2bf(silu_f(hn));
                }
        }
    }
    __syncthreads();

    // MM3 (AB) + MM4 (gate)
    {
        v8bf a[2][4];
        #pragma unroll
        for (int g = 0; g < 2; ++g)
            #pragma unroll
            for (int ks = 0; ks < 4; ++ks)
                a[g][ks] = *(const v8bf*)(A2 + (16*g + r16)*140 + ks*32 + quad*8);

        #pragma unroll
        for (int c2 = 0; c2 < 4; ++c2) {
            const int ch = (wv*4 + c2)*16 + r16;
            v4f acc[2] = {(v4f){0,0,0,0}, (v4f){0,0,0,0}};
            #pragma unroll
            for (int ks = 0; ks < 4; ++ks) {
                const v8bf bb = *(const v8bf*)(Wd1t + (size_t)ch*128 + ks*32 + quad*8);
                acc[0] = __builtin_amdgcn_mfma_f32_16x16x32_bf16(a[0][ks], bb, acc[0], 0, 0, 0);
                acc[1] = __builtin_amdgcn_mfma_f32_16x16x32_bf16(a[1][ks], bb, acc[1], 0, 0, 0);
            }
            const float fb = (ch < 128) ? bd1[ch] : 0.0f;
            #pragma unroll
            for (int g = 0; g < 2; ++g)
                #pragma unroll
                for (int rr = 0; rr < 4; ++rr)
                    AB[(size_t)(base + 16*g + quad*4 + rr)*256 + ch] = acc[g][rr] + fb;
        }

        #pragma unroll
        for (int c2 = 0; c2 < 2; ++c2) {
            const int ch = (wv*2 + c2)*16 + r16;
            v4f acc[2] = {(v4f){0,0,0,0}, (v4f){0,0,0,0}};
            #pragma unroll
            for (int ks = 0; ks < 4; ++ks) {
                const v8bf bb = *(const v8bf*)(Wp1t + (size_t)ch*128 + ks*32 + quad*8);
                acc[0] = __builtin_amdgcn_mfma_f32_16x16x32_bf16(a[0][ks], bb, acc[0], 0, 0, 0);
                acc[1] = __builtin_amdgcn_mfma_f32_16x16x32_bf16(a[1][ks], bb, acc[1], 0, 0, 0);
            }
            const float bc = bp1[ch];
            #pragma unroll
            for (int g = 0; g < 2; ++g)
                #pragma unroll
                for (int rr = 0; rr < 4; ++rr) {
                    const int row = 16*g + quad*4 + rr;
                    const float gg = sigm_f(acc[g][rr] + bc);
                    const float x = emb[sInt[row]*128 + ch] * gg;
                    A3[row*140 + ch] = f2bf(silu_f(x));
                }
        }
    }
    __syncthreads();

    // MM5: A3 @ Wr1t -> silu -> A1
    {
        v8bf a[2][4];
        #pragma unroll
        for (int g = 0; g < 2; ++g)
            #pragma unroll
            for (int ks = 0; ks < 4; ++ks)
                a[g][ks] = *(const v8bf*)(A3 + (16*g + r16)*140 + ks*32 + quad*8);
        #pragma unroll
        for (int c2 = 0; c2 < 2; ++c2) {
            const int ch = (wv*2 + c2)*16 + r16;
            v4f acc[2] = {(v4f){0,0,0,0}, (v4f){0,0,0,0}};
            #pragma unroll
            for (int ks = 0; ks < 4; ++ks) {
                const v8bf bb = *(const v8bf*)(Wr1t + (size_t)ch*128 + ks*32 + quad*8);
                acc[0] = __builtin_amdgcn_mfma_f32_16x16x32_bf16(a[0][ks], bb, acc[0], 0, 0, 0);
                acc[1] = __builtin_amdgcn_mfma_f32_16x16x32_bf16(a[1][ks], bb, acc[1], 0, 0, 0);
            }
            const float bc = br1[ch];
            #pragma unroll
            for (int g = 0; g < 2; ++g)
                #pragma unroll
                for (int rr = 0; rr < 4; ++rr)
                    A1[(16*g + quad*4 + rr)*140 + ch] = f2bf(silu_f(acc[g][rr] + bc));
        }
    }
    __syncthreads();

    // MM6: logits
    {
        const int g = wv >> 1, ct = wv & 1;
        v8bf a[4];
        #pragma unroll
        for (int ks = 0; ks < 4; ++ks)
            a[ks] = *(const v8bf*)(A1 + (16*g + r16)*140 + ks*32 + quad*8);
        v4f acc = (v4f){0,0,0,0};
        #pragma unroll
        for (int ks = 0; ks < 4; ++ks) {
            const v8bf bb = *(const v8bf*)(Wr2t + (size_t)(ct*16 + r16)*128 + ks*32 + quad*8);
            acc = __builtin_amdgcn_mfma_f32_16x16x32_bf16(a[ks], bb, acc, 0, 0, 0);
        }
        const int col = ct*16 + r16;
        if (col < NCLS) {
            const float bc = br2[col];
            #pragma unroll
            for (int rr = 0; rr < 4; ++rr)
                outL[(size_t)(base + 16*g + quad*4 + rr)*NCLS + col] = acc[rr] + bc;
        }
    }

    // X_out tail
    for (int o = tid; o < 32*CC*3; o += 256) {
        const int r = o / (CC*3), q = o % (CC*3);
        const int node = base + r;
        const int bq = node >> 10;
        const int cq = q / 3, dc = q % 3;
        const float xv = X[((size_t)node*CC + cq)*3 + dc];
        float a = 0.0f;
        for (int k = 0; k < KNN; ++k) {
            const int j = idxb[(size_t)node*KNN + k];
            const float xjv = X[(((size_t)(bq << 10) + j)*CC + cq)*3 + dc];
            a += (xv - xjv) * wbuf[(size_t)node*KNN + k];
        }
        outX[(size_t)node*CC*3 + q] = xv + a / 9.0f;
    }
}

// ---------------- K6: pd, 8 nodes/block ----------------
__global__ __launch_bounds__(256) void k_pd2(
    const float* __restrict__ AB, const int* __restrict__ idxb,
    const float* __restrict__ Wd2, const float* __restrict__ bd2,
    float* __restrict__ outPd)
{
    const int tid  = threadIdx.x;
    const int lane = tid & 63, wv = tid >> 6;
    const int c0   = lane, c1 = lane + 64;
    const float w0 = Wd2[c0], w1 = Wd2[c1];
    const float b2 = 2.0f * bd2[0];

    #pragma unroll
    for (int s = 0; s < 2; ++s) {
        const int node = blockIdx.x * 8 + wv*2 + s;
        const int b    = node >> 10;

        int jv = 0;
        if (lane < KNN) jv = idxb[(size_t)node*KNN + lane];

        const float An0 = AB[(size_t)node*256 + c0];
        const float An1 = AB[(size_t)node*256 + c1];
        const float Bn0 = AB[(size_t)node*256 + 128 + c0];
        const float Bn1 = AB[(size_t)node*256 + 128 + c1];

        float Aj0[KNN], Aj1[KNN], Bj0[KNN], Bj1[KNN];
        #pragma unroll
        for (int e = 0; e < KNN; ++e) {
            const size_t jn = (size_t)((b << 10) + __shfl(jv, e)) * 256;
            Aj0[e] = AB[jn + c0];       Aj1[e] = AB[jn + c1];
            Bj0[e] = AB[jn + 128 + c0]; Bj1[e] = AB[jn + 128 + c1];
        }
        #pragma unroll
        for (int e = 0; e < KNN; ++e) {
            float p = (silu_f(An0 + Bj0[e]) + silu_f(Aj0[e] + Bn0)) * w0
                    + (silu_f(An1 + Bj1[e]) + silu_f(Aj1[e] + Bn1)) * w1;
            #pragma unroll
            for (int off = 32; off; off >>= 1) p += __shfl_xor(p, off, 64);
            if (lane == 0) outPd[(size_t)node*KNN + e] = p + b2;
        }
    }
}

extern "C" void kernel_launch(void* const* d_in, const int* in_sizes, int n_in,
                              void* d_out, int out_size, void* d_ws, size_t ws_size,
                              hipStream_t stream)
{
    const float* X   = (const float*)d_in[0];
    const int*   S   = (const int*)  d_in[1];
    const float* t   = (const float*)d_in[2];
    const float* emb = (const float*)d_in[3];
    const float* Wt1 = (const float*)d_in[4];
    const float* bt1 = (const float*)d_in[5];
    const float* Wt2 = (const float*)d_in[6];
    const float* bt2 = (const float*)d_in[7];
    const float* We1 = (const float*)d_in[8];
    const float* be1 = (const float*)d_in[9];
    const float* We2 = (const float*)d_in[10];
    const float* be2 = (const float*)d_in[11];
    const float* Wx1 = (const float*)d_in[12];
    const float* bx1 = (const float*)d_in[13];
    const float* Wx2 = (const float*)d_in[14];
    const float* bx2 = (const float*)d_in[15];
    const float* Wh1 = (const float*)d_in[16];
    const float* bh1 = (const float*)d_in[17];
    const float* Wh2 = (const float*)d_in[18];
    const float* bh2 = (const float*)d_in[19];
    const float* Wd1 = (const float*)d_in[20];
    const float* bd1 = (const float*)d_in[21];
    const float* Wd2 = (const float*)d_in[22];
    const float* bd2 = (const float*)d_in[23];
    const float* Wp1 = (const float*)d_in[24];
    const float* bp1 = (const float*)d_in[25];
    const float* Wr1 = (const float*)d_in[26];
    const float* br1 = (const float*)d_in[27];
    const float* Wr2 = (const float*)d_in[28];
    const float* br2 = (const float*)d_in[29];

    float* out   = (float*)d_out;
    float* outL  = out;
    float* outX  = out + (size_t)BN*NCLS;
    float* outPd = outX + (size_t)BN*CC*3;

    unsigned short* WeF   = (unsigned short*)d_ws;   // 16384 (folded symmetric)
    unsigned short* We2t  = WeF   + 16384;
    unsigned short* Wx1t  = We2t  + 16384;
    unsigned short* Wh1t  = Wx1t  + 16384;           // 32768
    unsigned short* Wh2t  = Wh1t  + 32768;
    unsigned short* Wd1t  = Wh2t  + 16384;           // 32768
    unsigned short* Wp1t  = Wd1t  + 32768;
    unsigned short* Wr1t  = Wp1t  + 16384;
    unsigned short* Wt1t  = Wr1t  + 16384;
    unsigned short* Wt2t  = Wt1t  + 16384;
    unsigned short* We1Ft = Wt2t  + 16384;           // 32768
    unsigned short* Wr2t  = We1Ft + 32768;           // 4096
    float* Hh   = (float*)(Wr2t + 4096);
    float* msum = Hh   + (size_t)BN*EDIM;
    float* Hn   = msum + (size_t)BN*HDIM;
    float* wbuf = Hn   + (size_t)BN*EDIM;
    float* P    = wbuf + (size_t)BN*KNN;
    int*   idxb = (int*)(P + (size_t)BN*256);

    k_prep   <<<912,            256, 0, stream>>>(We1, We2, Wx1, Wh1, Wh2, Wd1, Wp1, Wr1, Wt1, Wt2, Wr2,
                                                  WeF, We2t, Wx1t, Wh1t, Wh2t, Wd1t, Wp1t, Wr1t,
                                                  Wt1t, Wt2t, We1Ft, Wr2t);
    k_hhPknn <<<BN/32 + BN/64,  256, 0, stream>>>(t, S, emb, Wt1t, bt1, Wt2t, bt2, We1Ft, be1,
                                                  Hh, P, X, idxb);
    k_edge   <<<BN/16,          256, 0, stream>>>(X, idxb, P, WeF, We2t, Wx1t,
                                                  be2, bx1, Wx2, bx2, msum, wbuf);
    k_nodeF  <<<BN/32,          256, 0, stream>>>(X, Hh, msum, idxb, wbuf,
                                                  Wh1t, bh1, Wh2t, bh2, Wd1t, bd1,
                                                  S, emb, Wp1t, bp1, Wr1t, br1, Wr2t, br2,
                                                  Hn, P, outL, outX);
    k_pd2    <<<BN/8,           256, 0, stream>>>(P, idxb, Wd2, bd2, outPd);
}

// Round 13
// 415.992 us; speedup vs baseline: 1.0181x; 1.0181x over previous
//
#include <hip/hip_runtime.h>

#define BATCH 32
#define NPT   1024
#define CC    14
#define KNN   9
#define EDIM  128
#define HDIM  128
#define NCLS  25
#define BN    (BATCH*NPT)

#define RSTR  132     // radF row stride (ushort): 66 dw -> start bank 2*r (distinct)
#define SSTR  140     // sil row stride (ushort): 70 dw -> start bank 6*r (distinct)

typedef float  v4f __attribute__((ext_vector_type(4)));
typedef __bf16 v8bf __attribute__((ext_vector_type(8)));

// symmetric-pair enumeration (c<=e) of the 14x14 radial matrix: 105 entries
__device__ const unsigned char PC_tab[105] = {
    0,0,0,0,0,0,0,0,0,0,0,0,0,0,
    1,1,1,1,1,1,1,1,1,1,1,1,1,
    2,2,2,2,2,2,2,2,2,2,2,2,
    3,3,3,3,3,3,3,3,3,3,3,
    4,4,4,4,4,4,4,4,4,4,
    5,5,5,5,5,5,5,5,5,
    6,6,6,6,6,6,6,6,
    7,7,7,7,7,7,7,
    8,8,8,8,8,8,
    9,9,9,9,9,
    10,10,10,10,
    11,11,11,
    12,12,
    13};
__device__ const unsigned char PE_tab[105] = {
    0,1,2,3,4,5,6,7,8,9,10,11,12,13,
    1,2,3,4,5,6,7,8,9,10,11,12,13,
    2,3,4,5,6,7,8,9,10,11,12,13,
    3,4,5,6,7,8,9,10,11,12,13,
    4,5,6,7,8,9,10,11,12,13,
    5,6,7,8,9,10,11,12,13,
    6,7,8,9,10,11,12,13,
    7,8,9,10,11,12,13,
    8,9,10,11,12,13,
    9,10,11,12,13,
    10,11,12,13,
    11,12,13,
    12,13,
    13};

__device__ __forceinline__ float silu_f(float x) {
    const float e = __expf(-x);
    return x * __builtin_amdgcn_rcpf(1.0f + e);
}
__device__ __forceinline__ float sigm_f(float x) {
    const float e = __expf(-x);
    return __builtin_amdgcn_rcpf(1.0f + e);
}

__device__ __forceinline__ unsigned short f2bf_rne(float f) {
    union { float f; unsigned u; } v; v.f = f;
    unsigned r = v.u + 0x7fffu + ((v.u >> 16) & 1u);
    return (unsigned short)(r >> 16);
}
__device__ __forceinline__ unsigned short f2bf(float f) {
    union { float f; unsigned u; } v; v.f = f;
    return (unsigned short)((v.u + 0x8000u) >> 16);
}

// ---------------- K0: weight prep (transpose + bf16 + symmetric fold) ----------------
__global__ __launch_bounds__(256) void k_prep(
    const float* __restrict__ We1, const float* __restrict__ We2,
    const float* __restrict__ Wx1, const float* __restrict__ Wh1,
    const float* __restrict__ Wh2, const float* __restrict__ Wd1,
    const float* __restrict__ Wp1, const float* __restrict__ Wr1,
    const float* __restrict__ Wt1, const float* __restrict__ Wt2,
    const float* __restrict__ Wr2,
    unsigned short* __restrict__ WeF,  unsigned short* __restrict__ We2t,
    unsigned short* __restrict__ Wx1t, unsigned short* __restrict__ Wh1t,
    unsigned short* __restrict__ Wh2t, unsigned short* __restrict__ Wd1t,
    unsigned short* __restrict__ Wp1t, unsigned short* __restrict__ Wr1t,
    unsigned short* __restrict__ Wt1t, unsigned short* __restrict__ Wt2t,
    unsigned short* __restrict__ We1Ft, unsigned short* __restrict__ Wr2t)
{
    int i = blockIdx.x * 256 + threadIdx.x;
    if (i < 16384) {   // folded symmetric radial weights: [ch][k<=127], K=105 real
        const int ch = i >> 7, k = i & 127;
        float v = 0.0f;
        if (k < 105) {
            const int c = PC_tab[k], e = PE_tab[k];
            v = We1[(size_t)(256 + c*14 + e)*128 + ch];
            if (c != e) v += We1[(size_t)(256 + e*14 + c)*128 + ch];
        }
        WeF[i] = f2bf_rne(v);
        return;
    }
    i -= 16384;
    if (i < 16384) { We2t[i] = f2bf_rne(We2[(size_t)(i % 128)*128 + i/128]); return; }
    i -= 16384;
    if (i < 16384) { Wx1t[i] = f2bf_rne(Wx1[(size_t)(i % 128)*128 + i/128]); return; }
    i -= 16384;
    if (i < 32768) { const int c = i/256, k = i%256; Wh1t[i] = f2bf_rne(Wh1[(size_t)k*128 + c]); return; }
    i -= 32768;
    if (i < 16384) { Wh2t[i] = f2bf_rne(Wh2[(size_t)(i % 128)*128 + i/128]); return; }
    i -= 16384;
    if (i < 32768) {
        const int t = i/128, k = i%128;
        Wd1t[i] = f2bf_rne((t < 128) ? Wd1[(size_t)k*128 + t] : Wd1[(size_t)(128 + k)*128 + (t - 128)]);
        return;
    }
    i -= 32768;
    if (i < 16384) { Wp1t[i] = f2bf_rne(Wp1[(size_t)(i % 128)*128 + i/128]); return; }
    i -= 16384;
    if (i < 16384) { Wr1t[i] = f2bf_rne(Wr1[(size_t)(i % 128)*128 + i/128]); return; }
    i -= 16384;
    if (i < 16384) { Wt1t[i] = f2bf_rne(Wt1[(size_t)(i % 128)*128 + i/128]); return; }
    i -= 16384;
    if (i < 16384) { Wt2t[i] = f2bf_rne(Wt2[(size_t)(i % 128)*128 + i/128]); return; }
    i -= 16384;
    if (i < 32768) {
        const float* q = (i/128 < 128) ? &We1[(size_t)(i%128)*128 + i/128]
                                       : &We1[(size_t)(128 + i%128)*128 + (i/128 - 128)];
        We1Ft[i] = f2bf_rne(*q);
        return;
    }
    i -= 32768;
    if (i < 4096) {    // logits weight: [ch 0..31][k 0..127], ch>=25 zero
        const int ch = i >> 7, k = i & 127;
        Wr2t[i] = (ch < NCLS) ? f2bf_rne(Wr2[(size_t)k*NCLS + ch]) : (unsigned short)0;
    }
}

// ---------------- K1: FUSED hhP (blocks 0..1023) + knn (blocks 1024..1535) ----------------
__global__ __launch_bounds__(256) void k_hhPknn(
    const float* __restrict__ t, const int* __restrict__ S,
    const float* __restrict__ emb,
    const unsigned short* __restrict__ Wt1t, const float* __restrict__ bt1,
    const unsigned short* __restrict__ Wt2t, const float* __restrict__ bt2,
    const unsigned short* __restrict__ We1Ft, const float* __restrict__ be1,
    float* __restrict__ Hh, float* __restrict__ P,
    const float* __restrict__ X, int* __restrict__ idxb)
{
    __shared__ __align__(16) unsigned char smem[34816];
    const int tid = threadIdx.x;

    if (blockIdx.x < BN/32) {
        // ================= hhP =================
        unsigned short* A0 = (unsigned short*)smem;
        unsigned short* A1 = A0 + 32*140;
        unsigned short* A2 = A1 + 32*140;
        int*            sInt = (int*)(A2 + 32*140);

        const int wv   = tid >> 6, lane = tid & 63;
        const int quad = lane >> 4, r16 = lane & 15;
        const int col  = tid & 127, rh = tid >> 7;
        const int base = blockIdx.x * 32;

        if (tid < 32) sInt[tid] = S[base + tid];

        const float step  = 1.0f / 127.0f;
        const float coeff = -0.5f / (step * step);
        const float off   = step * (float)col;
        #pragma unroll
        for (int rr = 0; rr < 16; ++rr) {
            const int r = rh*16 + rr;
            const float d = t[base + r] - off + 1e-6f;
            A0[r*140 + col] = f2bf(__expf(coeff * d * d));
        }
        __syncthreads();

        // MM_t1
        {
            v8bf a[2][4];
            #pragma unroll
            for (int g = 0; g < 2; ++g)
                #pragma unroll
                for (int ks = 0; ks < 4; ++ks)
                    a[g][ks] = *(const v8bf*)(A0 + (16*g + r16)*140 + ks*32 + quad*8);
            #pragma unroll
            for (int c2 = 0; c2 < 2; ++c2) {
                const int ch = (wv*2 + c2)*16 + r16;
                v4f acc[2] = {(v4f){0,0,0,0}, (v4f){0,0,0,0}};
                #pragma unroll
                for (int ks = 0; ks < 4; ++ks) {
                    const v8bf bb = *(const v8bf*)(Wt1t + (size_t)ch*128 + ks*32 + quad*8);
                    acc[0] = __builtin_amdgcn_mfma_f32_16x16x32_bf16(a[0][ks], bb, acc[0], 0, 0, 0);
                    acc[1] = __builtin_amdgcn_mfma_f32_16x16x32_bf16(a[1][ks], bb, acc[1], 0, 0, 0);
                }
                const float bc = bt1[ch];
                #pragma unroll
                for (int g = 0; g < 2; ++g)
                    #pragma unroll
                    for (int rr = 0; rr < 4; ++rr)
                        A1[(16*g + quad*4 + rr)*140 + ch] = f2bf(fmaxf(acc[g][rr] + bc, 0.0f));
            }
        }
        __syncthreads();

        // MM_t2
        {
            v8bf a[2][4];
            #pragma unroll
            for (int g = 0; g < 2; ++g)
                #pragma unroll
                for (int ks = 0; ks < 4; ++ks)
                    a[g][ks] = *(const v8bf*)(A1 + (16*g + r16)*140 + ks*32 + quad*8);
            #pragma unroll
            for (int c2 = 0; c2 < 2; ++c2) {
                const int ch = (wv*2 + c2)*16 + r16;
                v4f acc[2] = {(v4f){0,0,0,0}, (v4f){0,0,0,0}};
                #pragma unroll
                for (int ks = 0; ks < 4; ++ks) {
                    const v8bf bb = *(const v8bf*)(Wt2t + (size_t)ch*128 + ks*32 + quad*8);
                    acc[0] = __builtin_amdgcn_mfma_f32_16x16x32_bf16(a[0][ks], bb, acc[0], 0, 0, 0);
                    acc[1] = __builtin_amdgcn_mfma_f32_16x16x32_bf16(a[1][ks], bb, acc[1], 0, 0, 0);
                }
                const float bc = bt2[ch];
                #pragma unroll
                for (int g = 0; g < 2; ++g)
                    #pragma unroll
                    for (int rr = 0; rr < 4; ++rr) {
                        const int row = 16*g + quad*4 + rr;
                        const int node = base + row;
                        const float hh = emb[sInt[row]*128 + ch] + acc[g][rr] + bc;
                        Hh[(size_t)node*128 + ch] = hh;
                        A2[row*140 + ch] = f2bf(silu_f(hh));
                    }
            }
        }
        __syncthreads();

        // MM_P
        {
            v8bf a[2][4];
            #pragma unroll
            for (int g = 0; g < 2; ++g)
                #pragma unroll
                for (int ks = 0; ks < 4; ++ks)
                    a[g][ks] = *(const v8bf*)(A2 + (16*g + r16)*140 + ks*32 + quad*8);
            #pragma unroll
            for (int c2 = 0; c2 < 4; ++c2) {
                const int ch = (wv*4 + c2)*16 + r16;
                v4f acc[2] = {(v4f){0,0,0,0}, (v4f){0,0,0,0}};
                #pragma unroll
                for (int ks = 0; ks < 4; ++ks) {
                    const v8bf bb = *(const v8bf*)(We1Ft + (size_t)ch*128 + ks*32 + quad*8);
                    acc[0] = __builtin_amdgcn_mfma_f32_16x16x32_bf16(a[0][ks], bb, acc[0], 0, 0, 0);
                    acc[1] = __builtin_amdgcn_mfma_f32_16x16x32_bf16(a[1][ks], bb, acc[1], 0, 0, 0);
                }
                const float fb = (ch < 128) ? be1[ch] : 0.0f;
                #pragma unroll
                for (int g = 0; g < 2; ++g)
                    #pragma unroll
                    for (int rr = 0; rr < 4; ++rr)
                        P[(size_t)(base + 16*g + quad*4 + rr)*256 + ch] = acc[g][rr] + fb;
            }
        }
        return;
    }

    // ================= knn =================
    {
        float4* Cc   = (float4*)smem;
        float*  dshp = (float*)(smem + 16384);
        int*    ishp = (int*)  (smem + 25600);

        const int kb = blockIdx.x - BN/32;
        const int lane = tid & 63, wv = tid >> 6;
        const int bb = kb >> 4;
        const int n0 = (kb & 15) << 6;
        const float* Xb = X + (size_t)bb * NPT * 42;

        for (int i = tid; i < NPT; i += 256) {
            const float* p = Xb + (size_t)i*42 + 3;
            Cc[i] = make_float4(p[0], p[1], p[2], 0.0f);
        }
        __syncthreads();

        const int n = n0 + lane;
        const float4 c = Cc[n];

        float dist[KNN]; int ind[KNN];
        #pragma unroll
        for (int k = 0; k < KNN; ++k) { dist[k] = 3.0e38f; ind[k] = -1; }

        const int j0 = wv * 256;
        for (int jj = 0; jj < 256; ++jj) {
            const int j = j0 + jj;
            const float4 q = Cc[j];
            const float dx = __fsub_rn(c.x, q.x);
            const float dy = __fsub_rn(c.y, q.y);
            const float dz = __fsub_rn(c.z, q.z);
            float d = __fadd_rn(__fadd_rn(__fmul_rn(dx,dx), __fmul_rn(dy,dy)), __fmul_rn(dz,dz));
            if (j == n) d = __fadd_rn(d, 1e10f);
            if (d < dist[KNN-1]) {
                dist[KNN-1] = d; ind[KNN-1] = j;
                #pragma unroll
                for (int p = KNN-1; p > 0; --p) {
                    if (dist[p] < dist[p-1]) {
                        float td = dist[p]; dist[p] = dist[p-1]; dist[p-1] = td;
                        int   ti = ind[p];  ind[p]  = ind[p-1];  ind[p-1]  = ti;
                    }
                }
            }
        }
        #pragma unroll
        for (int k = 0; k < KNN; ++k) {
            dshp[((wv*64 + lane))*KNN + k] = dist[k];
            ishp[((wv*64 + lane))*KNN + k] = ind[k];
        }
        __syncthreads();

        if (tid < 64) {
            float fd[KNN]; int fi[KNN];
            #pragma unroll
            for (int k = 0; k < KNN; ++k) { fd[k] = 3.0e38f; fi[k] = -1; }
            for (int w = 0; w < 4; ++w)
                #pragma unroll
                for (int k = 0; k < KNN; ++k) {
                    const float d = dshp[(w*64 + tid)*KNN + k];
                    const int   i = ishp[(w*64 + tid)*KNN + k];
                    if (d < fd[KNN-1]) {
                        fd[KNN-1] = d; fi[KNN-1] = i;
                        #pragma unroll
                        for (int p = KNN-1; p > 0; --p) {
                            if (fd[p] < fd[p-1]) {
                                float td = fd[p]; fd[p] = fd[p-1]; fd[p-1] = td;
                                int   ti = fi[p]; fi[p] = fi[p-1]; fi[p-1] = ti;
                            }
                        }
                    }
                }
            const int node = (bb << 10) + n0 + tid;
            #pragma unroll
            for (int k = 0; k < KNN; ++k) idxb[(size_t)node*KNN + k] = fi[k];
        }
    }
}

// ---------------- K4: MFMA edge pipeline, 16 nodes/block (R11 geometry) ----------------
__global__ __launch_bounds__(256) void k_edge(
    const float* __restrict__ X, const int* __restrict__ idxb,
    const float* __restrict__ P,
    const unsigned short* __restrict__ WeF,
    const unsigned short* __restrict__ We2t,
    const unsigned short* __restrict__ Wx1t,
    const float* __restrict__ be2,
    const float* __restrict__ bx1, const float* __restrict__ Wx2,
    const float* __restrict__ bx2,
    float* __restrict__ msum, float* __restrict__ wbuf)
{
    __shared__ unsigned short radF[16*RSTR];           // 4224 B
    __shared__ unsigned short silA[16*SSTR];           // 4480 B
    __shared__ unsigned short silB[16*SSTR];           // 4480 B
    __shared__ __align__(16) float relS[16][57];       // 3648 B
    __shared__ float wred[KNN][16][4];                 // 2304 B
    __shared__ int   jsh[16][KNN];                     //  576 B

    const int tid  = threadIdx.x;
    const int wv   = tid >> 6, lane = tid & 63;
    const int quad = lane >> 4, r16 = lane & 15;
    const int node0 = blockIdx.x * 16;
    const int b     = node0 >> 10;
    const int chan0 = (wv*2 + 0)*16 + r16;
    const int chan1 = (wv*2 + 1)*16 + r16;
    const int srow  = tid >> 4, c16 = tid & 15;

    if (tid < 144) jsh[tid/9][tid%9] = idxb[(size_t)(node0 + tid/9)*KNN + tid%9];

    // per-lane folded-feature pair offsets (loop-invariant), packed
    int offCE[7];
    #pragma unroll
    for (int kk = 0; kk < 7; ++kk) {
        const int f = c16 + 16*kk;
        if (f < 105) offCE[kk] = ((int)PC_tab[f]*4) | (((int)PE_tab[f]*4) << 16);
        else         offCE[kk] = 0;
    }
    // zero the K-pad (f 105..127) once
    {
        const int f6 = 96 + c16, f7 = 112 + c16;
        if (f6 >= 105) radF[srow*RSTR + f6] = 0;
        radF[srow*RSTR + f7] = 0;
    }

    // own-node coords in regs
    float xr[3] = {0,0,0};
    if (c16 < 14) {
        #pragma unroll
        for (int k = 0; k < 3; ++k)
            xr[k] = X[(size_t)(node0 + srow)*42 + c16*3 + k];
    }

    // Pn (constant over slots)
    float pn0[4], pn1[4];
    #pragma unroll
    for (int rr = 0; rr < 4; ++rr) {
        pn0[rr] = P[(size_t)(node0 + quad*4 + rr)*256 + chan0];
        pn1[rr] = P[(size_t)(node0 + quad*4 + rr)*256 + chan1];
    }
    const float be2c0 = be2[chan0], be2c1 = be2[chan1];
    const float bxc0  = bx1[chan0], bxc1  = bx1[chan1];
    const float wxc0  = Wx2[chan0], wxc1  = Wx2[chan1];

    // B-fragments (persistent across 9 tiles)
    v8bf B1[2][4], B2[2][4], B3[2][4];
    #pragma unroll
    for (int c2 = 0; c2 < 2; ++c2) {
        const int ct = wv*2 + c2;
        #pragma unroll
        for (int ks = 0; ks < 4; ++ks) {
            B1[c2][ks] = *(const v8bf*)(WeF  + (size_t)(ct*16 + r16)*128 + ks*32 + quad*8);
            B2[c2][ks] = *(const v8bf*)(We2t + (size_t)(ct*16 + r16)*128 + ks*32 + quad*8);
            B3[c2][ks] = *(const v8bf*)(Wx1t + (size_t)(ct*16 + r16)*128 + ks*32 + quad*8);
        }
    }

    float msA0[4] = {0,0,0,0}, msA1[4] = {0,0,0,0};

    __syncthreads();   // jsh ready

    // prefetch Xj for slot 0
    float xj[3] = {0,0,0};
    if (c16 < 14) {
        const int j = jsh[srow][0];
        #pragma unroll
        for (int k = 0; k < 3; ++k)
            xj[k] = X[(size_t)((b << 10) + j)*42 + c16*3 + k];
    }

    for (int t = 0; t < KNN; ++t) {
        // relS write (same-wave rows)
        if (c16 < 14) {
            #pragma unroll
            for (int k = 0; k < 3; ++k)
                relS[srow][c16*4 + k] = xr[k] - xj[k];
        }
        // prefetch next slot's Xj
        if (t + 1 < KNN && c16 < 14) {
            const int j = jsh[srow][t+1];
            #pragma unroll
            for (int k = 0; k < 3; ++k)
                xj[k] = X[(size_t)((b << 10) + j)*42 + c16*3 + k];
        }
        // prefetch pj for ep1
        float pj0[4], pj1[4];
        #pragma unroll
        for (int rr = 0; rr < 4; ++rr) {
            const int jq = jsh[quad*4 + rr][t];
            const size_t jrow = (size_t)((b << 10) + jq)*256 + 128;
            pj0[rr] = P[jrow + chan0];
            pj1[rr] = P[jrow + chan1];
        }

        // folded radial -> silu -> radF (105 features, same-wave relS reads)
        {
            const float* rb = relS[srow];
            #pragma unroll
            for (int kk = 0; kk < 7; ++kk) {
                const int f = c16 + 16*kk;
                if (f < 105) {
                    const int oc = offCE[kk] & 0xffff, oe = offCE[kk] >> 16;
                    const float v = (rb[oc]*rb[oe] + rb[oc+1]*rb[oe+1]
                                   + rb[oc+2]*rb[oe+2]) * (1.0f/14.0f);
                    radF[srow*RSTR + f] = f2bf(silu_f(v));
                }
            }
        }
        __syncthreads();   // B

        // ---- layer 1 MFMA (folded K=128) ----
        v4f acc10 = (v4f){0,0,0,0}, acc11 = (v4f){0,0,0,0};
        #pragma unroll
        for (int ks = 0; ks < 4; ++ks) {
            const v8bf a = *(const v8bf*)(radF + r16*RSTR + ks*32 + quad*8);
            acc10 = __builtin_amdgcn_mfma_f32_16x16x32_bf16(a, B1[0][ks], acc10, 0, 0, 0);
            acc11 = __builtin_amdgcn_mfma_f32_16x16x32_bf16(a, B1[1][ks], acc11, 0, 0, 0);
        }
        // ep1: + Pn + Pj, silu -> silA
        #pragma unroll
        for (int rr = 0; rr < 4; ++rr) {
            const int rw = quad*4 + rr;
            silA[rw*SSTR + chan0] = f2bf(silu_f(acc10[rr] + pn0[rr] + pj0[rr]));
            silA[rw*SSTR + chan1] = f2bf(silu_f(acc11[rr] + pn1[rr] + pj1[rr]));
        }
        __syncthreads();   // C

        // ---- layer 2 MFMA ----
        v4f acc20 = (v4f){0,0,0,0}, acc21 = (v4f){0,0,0,0};
        #pragma unroll
        for (int ks = 0; ks < 4; ++ks) {
            const v8bf a = *(const v8bf*)(silA + r16*SSTR + ks*32 + quad*8);
            acc20 = __builtin_amdgcn_mfma_f32_16x16x32_bf16(a, B2[0][ks], acc20, 0, 0, 0);
            acc21 = __builtin_amdgcn_mfma_f32_16x16x32_bf16(a, B2[1][ks], acc21, 0, 0, 0);
        }
        // ep2: msum accumulates in regs (rows ARE nodes)
        #pragma unroll
        for (int rr = 0; rr < 4; ++rr) {
            const float m0 = acc20[rr] + be2c0;
            const float m1 = acc21[rr] + be2c1;
            msA0[rr] += m0;  msA1[rr] += m1;
            const int rw = quad*4 + rr;
            silB[rw*SSTR + chan0] = f2bf(silu_f(m0));
            silB[rw*SSTR + chan1] = f2bf(silu_f(m1));
        }
        __syncthreads();   // D

        // ---- layer 3 MFMA ----
        v4f acc30 = (v4f){0,0,0,0}, acc31 = (v4f){0,0,0,0};
        #pragma unroll
        for (int ks = 0; ks < 4; ++ks) {
            const v8bf a = *(const v8bf*)(silB + r16*SSTR + ks*32 + quad*8);
            acc30 = __builtin_amdgcn_mfma_f32_16x16x32_bf16(a, B3[0][ks], acc30, 0, 0, 0);
            acc31 = __builtin_amdgcn_mfma_f32_16x16x32_bf16(a, B3[1][ks], acc31, 0, 0, 0);
        }
        // ep3
        #pragma unroll
        for (int rr = 0; rr < 4; ++rr) {
            float pr = silu_f(acc30[rr] + bxc0) * wxc0
                     + silu_f(acc31[rr] + bxc1) * wxc1;
            pr += __shfl_xor(pr, 1);
            pr += __shfl_xor(pr, 2);
            pr += __shfl_xor(pr, 4);
            pr += __shfl_xor(pr, 8);
            if (r16 == 0) wred[t][quad*4 + rr][wv] = pr;
        }
    }

    #pragma unroll
    for (int rr = 0; rr < 4; ++rr) {
        msum[(size_t)(node0 + quad*4 + rr)*128 + chan0] = msA0[rr];
        msum[(size_t)(node0 + quad*4 + rr)*128 + chan1] = msA1[rr];
    }
    __syncthreads();
    if (tid < 16*KNN) {
        const int tt = tid / 16, rw = tid % 16;
        wbuf[(size_t)(node0 + rw)*KNN + tt] =
            wred[tt][rw][0] + wred[tt][rw][1] + wred[tt][rw][2] + wred[tt][rw][3] + bx2[0];
    }
}

// ---------------- K5: fused node pipeline, all-MFMA, 32 nodes/block ----------------
__global__ __launch_bounds__(256) void k_nodeF(
    const float* __restrict__ X, const float* __restrict__ Hh,
    const float* __restrict__ msum, const int* __restrict__ idxb,
    const float* __restrict__ wbuf,
    const unsigned short* __restrict__ Wh1t, const float* __restrict__ bh1,
    const unsigned short* __restrict__ Wh2t, const float* __restrict__ bh2,
    const unsigned short* __restrict__ Wd1t, const float* __restrict__ bd1,
    const int* __restrict__ S, const float* __restrict__ emb,
    const unsigned short* __restrict__ Wp1t, const float* __restrict__ bp1,
    const unsigned short* __restrict__ Wr1t, const float* __restrict__ br1,
    const unsigned short* __restrict__ Wr2t, const float* __restrict__ br2,
    float* __restrict__ Hn, float* __restrict__ AB,
    float* __restrict__ outL, float* __restrict__ outX)
{
    __shared__ __align__(16) unsigned short A0[32*268];
    __shared__ __align__(16) unsigned short A1[32*140];
    __shared__ __align__(16) unsigned short A2[32*140];
    __shared__ __align__(16) unsigned short A3[32*140];
    __shared__ int sInt[32];

    const int tid  = threadIdx.x;
    const int wv   = tid >> 6, lane = tid & 63;
    const int quad = lane >> 4, r16 = lane & 15;
    const int base = blockIdx.x * 32;

    if (tid < 32) sInt[tid] = S[base + tid];
    for (int r = 0; r < 32; ++r) {
        const int node = base + r;
        const float v = (tid < 128) ? Hh[(size_t)node*128 + tid]
                                    : msum[(size_t)node*128 + (tid - 128)];
        A0[r*268 + tid] = f2bf(silu_f(v));
    }
    __syncthreads();

    // MM1: K=256
    {
        v8bf a[2][8];
        #pragma unroll
        for (int g = 0; g < 2; ++g)
            #pragma unroll
            for (int ks = 0; ks < 8; ++ks)
                a[g][ks] = *(const v8bf*)(A0 + (16*g + r16)*268 + ks*32 + quad*8);
        #pragma unroll
        for (int c2 = 0; c2 < 2; ++c2) {
            const int ch = (wv*2 + c2)*16 + r16;
            v4f acc[2] = {(v4f){0,0,0,0}, (v4f){0,0,0,0}};
            #pragma unroll
            for (int ks = 0; ks < 8; ++ks) {
                const v8bf bb = *(const v8bf*)(Wh1t + (size_t)ch*256 + ks*32 + quad*8);
                acc[0] = __builtin_amdgcn_mfma_f32_16x16x32_bf16(a[0][ks], bb, acc[0], 0, 0, 0);
                acc[1] = __builtin_amdgcn_mfma_f32_16x16x32_bf16(a[1][ks], bb, acc[1], 0, 0, 0);
            }
            const float bc = bh1[ch];
            #pragma unroll
            for (int g = 0; g < 2; ++g)
                #pragma unroll
                for (int rr = 0; rr < 4; ++rr)
                    A1[(16*g + quad*4 + rr)*140 + ch] = f2bf(silu_f(acc[g][rr] + bc));
        }
    }
    __syncthreads();

    // MM2
    {
        v8bf a[2][4];
        #pragma unroll
        for (int g = 0; g < 2; ++g)
            #pragma unroll
            for (int ks = 0; ks < 4; ++ks)
                a[g][ks] = *(const v8bf*)(A1 + (16*g + r16)*140 + ks*32 + quad*8);
        #pragma unroll
        for (int c2 = 0; c2 < 2; ++c2) {
            const int ch = (wv*2 + c2)*16 + r16;
            v4f acc[2] = {(v4f){0,0,0,0}, (v4f){0,0,0,0}};
            #pragma unroll
            for (int ks = 0; ks < 4; ++ks) {
                const v8bf bb = *(const v8bf*)(Wh2t + (size_t)ch*128 + ks*32 + quad*8);
                acc[0] = __builtin_amdgcn_mfma_f32_16x16x32_bf16(a[0][ks], bb, acc[0], 0, 0, 0);
                acc[1] = __builtin_amdgcn_mfma_f32_16x16x32_bf16(a[1][ks], bb, acc[1], 0, 0, 0);
            }
            const float bc = bh2[ch];
            #pragma unroll
            for (int g = 0; g < 2; ++g)
                #pragma unroll
                for (int rr = 0; rr < 4; ++rr) {
                    const int row = 16*g + quad*4 + rr;
                    const int node = base + row;
                    const float hn = Hh[(size_t)node*128 + ch] + acc[g][rr] + bc;
                    Hn[(size_t)node*128 + ch] = hn;
                    A2[row*140 + ch] = f2bf(silu_f(hn));
                }
        }
    }
    __syncthreads();

    // MM3 (AB) + MM4 (gate)
    {
        v8bf a[2][4];
        #pragma unroll
        for (int g = 0; g < 2; ++g)
            #pragma unroll
            for (int ks = 0; ks < 4; ++ks)
                a[g][ks] = *(const v8bf*)(A2 + (16*g + r16)*140 + ks*32 + quad*8);

        #pragma unroll
        for (int c2 = 0; c2 < 4; ++c2) {
            const int ch = (wv*4 + c2)*16 + r16;
            v4f acc[2] = {(v4f){0,0,0,0}, (v4f){0,0,0,0}};
            #pragma unroll
            for (int ks = 0; ks < 4; ++ks) {
                const v8bf bb = *(const v8bf*)(Wd1t + (size_t)ch*128 + ks*32 + quad*8);
                acc[0] = __builtin_amdgcn_mfma_f32_16x16x32_bf16(a[0][ks], bb, acc[0], 0, 0, 0);
                acc[1] = __builtin_amdgcn_mfma_f32_16x16x32_bf16(a[1][ks], bb, acc[1], 0, 0, 0);
            }
            const float fb = (ch < 128) ? bd1[ch] : 0.0f;
            #pragma unroll
            for (int g = 0; g < 2; ++g)
                #pragma unroll
                for (int rr = 0; rr < 4; ++rr)
                    AB[(size_t)(base + 16*g + quad*4 + rr)*256 + ch] = acc[g][rr] + fb;
        }

        #pragma unroll
        for (int c2 = 0; c2 < 2; ++c2) {
            const int ch = (wv*2 + c2)*16 + r16;
            v4f acc[2] = {(v4f){0,0,0,0}, (v4f){0,0,0,0}};
            #pragma unroll
            for (int ks = 0; ks < 4; ++ks) {
                const v8bf bb = *(const v8bf*)(Wp1t + (size_t)ch*128 + ks*32 + quad*8);
                acc[0] = __builtin_amdgcn_mfma_f32_16x16x32_bf16(a[0][ks], bb, acc[0], 0, 0, 0);
                acc[1] = __builtin_amdgcn_mfma_f32_16x16x32_bf16(a[1][ks], bb, acc[1], 0, 0, 0);
            }
            const float bc = bp1[ch];
            #pragma unroll
            for (int g = 0; g < 2; ++g)
                #pragma unroll
                for (int rr = 0; rr < 4; ++rr) {
                    const int row = 16*g + quad*4 + rr;
                    const float gg = sigm_f(acc[g][rr] + bc);
                    const float x = emb[sInt[row]*128 + ch] * gg;
                    A3[row*140 + ch] = f2bf(silu_f(x));
                }
        }
    }
    __syncthreads();

    // MM5: A3 @ Wr1t -> silu -> A1
    {
        v8bf a[2][4];
        #pragma unroll
        for (int g = 0; g < 2; ++g)
            #pragma unroll
            for (int ks = 0; ks < 4; ++ks)
                a[g][ks] = *(const v8bf*)(A3 + (16*g + r16)*140 + ks*32 + quad*8);
        #pragma unroll
        for (int c2 = 0; c2 < 2; ++c2) {
            const int ch = (wv*2 + c2)*16 + r16;
            v4f acc[2] = {(v4f){0,0,0,0}, (v4f){0,0,0,0}};
            #pragma unroll
            for (int ks = 0; ks < 4; ++ks) {
                const v8bf bb = *(const v8bf*)(Wr1t + (size_t)ch*128 + ks*32 + quad*8);
                acc[0] = __builtin_amdgcn_mfma_f32_16x16x32_bf16(a[0][ks], bb, acc[0], 0, 0, 0);
                acc[1] = __builtin_amdgcn_mfma_f32_16x16x32_bf16(a[1][ks], bb, acc[1], 0, 0, 0);
            }
            const float bc = br1[ch];
            #pragma unroll
            for (int g = 0; g < 2; ++g)
                #pragma unroll
                for (int rr = 0; rr < 4; ++rr)
                    A1[(16*g + quad*4 + rr)*140 + ch] = f2bf(silu_f(acc[g][rr] + bc));
        }
    }
    __syncthreads();

    // MM6: logits
    {
        const int g = wv >> 1, ct = wv & 1;
        v8bf a[4];
        #pragma unroll
        for (int ks = 0; ks < 4; ++ks)
            a[ks] = *(const v8bf*)(A1 + (16*g + r16)*140 + ks*32 + quad*8);
        v4f acc = (v4f){0,0,0,0};
        #pragma unroll
        for (int ks = 0; ks < 4; ++ks) {
            const v8bf bb = *(const v8bf*)(Wr2t + (size_t)(ct*16 + r16)*128 + ks*32 + quad*8);
            acc = __builtin_amdgcn_mfma_f32_16x16x32_bf16(a[ks], bb, acc, 0, 0, 0);
        }
        const int col = ct*16 + r16;
        if (col < NCLS) {
            const float bc = br2[col];
            #pragma unroll
            for (int rr = 0; rr < 4; ++rr)
                outL[(size_t)(base + 16*g + quad*4 + rr)*NCLS + col] = acc[rr] + bc;
        }
    }

    // X_out tail
    for (int o = tid; o < 32*CC*3; o += 256) {
        const int r = o / (CC*3), q = o % (CC*3);
        const int node = base + r;
        const int bq = node >> 10;
        const int cq = q / 3, dc = q % 3;
        const float xv = X[((size_t)node*CC + cq)*3 + dc];
        float a = 0.0f;
        for (int k = 0; k < KNN; ++k) {
            const int j = idxb[(size_t)node*KNN + k];
            const float xjv = X[(((size_t)(bq << 10) + j)*CC + cq)*3 + dc];
            a += (xv - xjv) * wbuf[(size_t)node*KNN + k];
        }
        outX[(size_t)node*CC*3 + q] = xv + a / 9.0f;
    }
}

// ---------------- K6: pd, 8 nodes/block ----------------
__global__ __launch_bounds__(256) void k_pd2(
    const float* __restrict__ AB, const int* __restrict__ idxb,
    const float* __restrict__ Wd2, const float* __restrict__ bd2,
    float* __restrict__ outPd)
{
    const int tid  = threadIdx.x;
    const int lane = tid & 63, wv = tid >> 6;
    const int c0   = lane, c1 = lane + 64;
    const float w0 = Wd2[c0], w1 = Wd2[c1];
    const float b2 = 2.0f * bd2[0];

    #pragma unroll
    for (int s = 0; s < 2; ++s) {
        const int node = blockIdx.x * 8 + wv*2 + s;
        const int b    = node >> 10;

        int jv = 0;
        if (lane < KNN) jv = idxb[(size_t)node*KNN + lane];

        const float An0 = AB[(size_t)node*256 + c0];
        const float An1 = AB[(size_t)node*256 + c1];
        const float Bn0 = AB[(size_t)node*256 + 128 + c0];
        const float Bn1 = AB[(size_t)node*256 + 128 + c1];

        float Aj0[KNN], Aj1[KNN], Bj0[KNN], Bj1[KNN];
        #pragma unroll
        for (int e = 0; e < KNN; ++e) {
            const size_t jn = (size_t)((b << 10) + __shfl(jv, e)) * 256;
            Aj0[e] = AB[jn + c0];       Aj1[e] = AB[jn + c1];
            Bj0[e] = AB[jn + 128 + c0]; Bj1[e] = AB[jn + 128 + c1];
        }
        #pragma unroll
        for (int e = 0; e < KNN; ++e) {
            float p = (silu_f(An0 + Bj0[e]) + silu_f(Aj0[e] + Bn0)) * w0
                    + (silu_f(An1 + Bj1[e]) + silu_f(Aj1[e] + Bn1)) * w1;
            #pragma unroll
            for (int off = 32; off; off >>= 1) p += __shfl_xor(p, off, 64);
            if (lane == 0) outPd[(size_t)node*KNN + e] = p + b2;
        }
    }
}

extern "C" void kernel_launch(void* const* d_in, const int* in_sizes, int n_in,
                              void* d_out, int out_size, void* d_ws, size_t ws_size,
                              hipStream_t stream)
{
    const float* X   = (const float*)d_in[0];
    const int*   S   = (const int*)  d_in[1];
    const float* t   = (const float*)d_in[2];
    const float* emb = (const float*)d_in[3];
    const float* Wt1 = (const float*)d_in[4];
    const float* bt1 = (const float*)d_in[5];
    const float* Wt2 = (const float*)d_in[6];
    const float* bt2 = (const float*)d_in[7];
    const float* We1 = (const float*)d_in[8];
    const float* be1 = (const float*)d_in[9];
    const float* We2 = (const float*)d_in[10];
    const float* be2 = (const float*)d_in[11];
    const float* Wx1 = (const float*)d_in[12];
    const float* bx1 = (const float*)d_in[13];
    const float* Wx2 = (const float*)d_in[14];
    const float* bx2 = (const float*)d_in[15];
    const float* Wh1 = (const float*)d_in[16];
    const float* bh1 = (const float*)d_in[17];
    const float* Wh2 = (const float*)d_in[18];
    const float* bh2 = (const float*)d_in[19];
    const float* Wd1 = (const float*)d_in[20];
    const float* bd1 = (const float*)d_in[21];
    const float* Wd2 = (const float*)d_in[22];
    const float* bd2 = (const float*)d_in[23];
    const float* Wp1 = (const float*)d_in[24];
    const float* bp1 = (const float*)d_in[25];
    const float* Wr1 = (const float*)d_in[26];
    const float* br1 = (const float*)d_in[27];
    const float* Wr2 = (const float*)d_in[28];
    const float* br2 = (const float*)d_in[29];

    float* out   = (float*)d_out;
    float* outL  = out;
    float* outX  = out + (size_t)BN*NCLS;
    float* outPd = outX + (size_t)BN*CC*3;

    unsigned short* WeF   = (unsigned short*)d_ws;   // 16384 (folded symmetric)
    unsigned short* We2t  = WeF   + 16384;
    unsigned short* Wx1t  = We2t  + 16384;
    unsigned short* Wh1t  = Wx1t  + 16384;           // 32768
    unsigned short* Wh2t  = Wh1t  + 32768;
    unsigned short* Wd1t  = Wh2t  + 16384;           // 32768
    unsigned short* Wp1t  = Wd1t  + 32768;
    unsigned short* Wr1t  = Wp1t  + 16384;
    unsigned short* Wt1t  = Wr1t  + 16384;
    unsigned short* Wt2t  = Wt1t  + 16384;
    unsigned short* We1Ft = Wt2t  + 16384;           // 32768
    unsigned short* Wr2t  = We1Ft + 32768;           // 4096
    float* Hh   = (float*)(Wr2t + 4096);
    float* msum = Hh   + (size_t)BN*EDIM;
    float* Hn   = msum + (size_t)BN*HDIM;
    float* wbuf = Hn   + (size_t)BN*EDIM;
    float* P    = wbuf + (size_t)BN*KNN;
    int*   idxb = (int*)(P + (size_t)BN*256);

    k_prep   <<<912,            256, 0, stream>>>(We1, We2, Wx1, Wh1, Wh2, Wd1, Wp1, Wr1, Wt1, Wt2, Wr2,
                                                  WeF, We2t, Wx1t, Wh1t, Wh2t, Wd1t, Wp1t, Wr1t,
                                                  Wt1t, Wt2t, We1Ft, Wr2t);
    k_hhPknn <<<BN/32 + BN/64,  256, 0, stream>>>(t, S, emb, Wt1t, bt1, Wt2t, bt2, We1Ft, be1,
                                                  Hh, P, X, idxb);
    k_edge   <<<BN/16,          256, 0, stream>>>(X, idxb, P, WeF, We2t, Wx1t,
                                                  be2, bx1, Wx2, bx2, msum, wbuf);
    k_nodeF  <<<BN/32,          256, 0, stream>>>(X, Hh, msum, idxb, wbuf,
                                                  Wh1t, bh1, Wh2t, bh2, Wd1t, bd1,
                                                  S, emb, Wp1t, bp1, Wr1t, br1, Wr2t, br2,
                                                  Hn, P, outL, outX);
    k_pd2    <<<BN/8,           256, 0, stream>>>(P, idxb, Wd2, bd2, outPd);
}

// Round 14
// 413.307 us; speedup vs baseline: 1.0247x; 1.0065x over previous
//
#include <hip/hip_runtime.h>

#define BATCH 32
#define NPT   1024
#define CC    14
#define KNN   9
#define EDIM  128
#define HDIM  128
#define NCLS  25
#define BN    (BATCH*NPT)

#define RSTR  132
#define SSTR  140

typedef float  v4f __attribute__((ext_vector_type(4)));
typedef __bf16 v8bf __attribute__((ext_vector_type(8)));

__device__ const unsigned char PC_tab[105] = {
    0,0,0,0,0,0,0,0,0,0,0,0,0,0,
    1,1,1,1,1,1,1,1,1,1,1,1,1,
    2,2,2,2,2,2,2,2,2,2,2,2,
    3,3,3,3,3,3,3,3,3,3,3,
    4,4,4,4,4,4,4,4,4,4,
    5,5,5,5,5,5,5,5,5,
    6,6,6,6,6,6,6,6,
    7,7,7,7,7,7,7,
    8,8,8,8,8,8,
    9,9,9,9,9,
    10,10,10,10,
    11,11,11,
    12,12,
    13};
__device__ const unsigned char PE_tab[105] = {
    0,1,2,3,4,5,6,7,8,9,10,11,12,13,
    1,2,3,4,5,6,7,8,9,10,11,12,13,
    2,3,4,5,6,7,8,9,10,11,12,13,
    3,4,5,6,7,8,9,10,11,12,13,
    4,5,6,7,8,9,10,11,12,13,
    5,6,7,8,9,10,11,12,13,
    6,7,8,9,10,11,12,13,
    7,8,9,10,11,12,13,
    8,9,10,11,12,13,
    9,10,11,12,13,
    10,11,12,13,
    11,12,13,
    12,13,
    13};

__device__ __forceinline__ float silu_f(float x) {
    const float e = __expf(-x);
    return x * __builtin_amdgcn_rcpf(1.0f + e);
}
__device__ __forceinline__ float sigm_f(float x) {
    const float e = __expf(-x);
    return __builtin_amdgcn_rcpf(1.0f + e);
}

__device__ __forceinline__ unsigned short f2bf_rne(float f) {
    union { float f; unsigned u; } v; v.f = f;
    unsigned r = v.u + 0x7fffu + ((v.u >> 16) & 1u);
    return (unsigned short)(r >> 16);
}
__device__ __forceinline__ unsigned short f2bf(float f) {
    union { float f; unsigned u; } v; v.f = f;
    return (unsigned short)((v.u + 0x8000u) >> 16);
}

// ---------------- K0: weight prep — ONLY what k_hhPknn reads ----------------
__global__ __launch_bounds__(256) void k_prep(
    const float* __restrict__ We1, const float* __restrict__ Wt1,
    const float* __restrict__ Wt2,
    unsigned short* __restrict__ Wt1t, unsigned short* __restrict__ Wt2t,
    unsigned short* __restrict__ We1Ft)
{
    int i = blockIdx.x * 256 + threadIdx.x;
    if (i < 16384) { Wt1t[i] = f2bf_rne(Wt1[(size_t)(i % 128)*128 + i/128]); return; }
    i -= 16384;
    if (i < 16384) { Wt2t[i] = f2bf_rne(Wt2[(size_t)(i % 128)*128 + i/128]); return; }
    i -= 16384;
    if (i < 32768) {
        const float* q = (i/128 < 128) ? &We1[(size_t)(i%128)*128 + i/128]
                                       : &We1[(size_t)(128 + i%128)*128 + (i/128 - 128)];
        We1Ft[i] = f2bf_rne(*q);
    }
}

// ---------------- K1: FUSED hhP [0,1024) + knn [1024,1536) + prep-rest [1536,2196) ----------------
__global__ __launch_bounds__(256) void k_hhPknn(
    const float* __restrict__ t, const int* __restrict__ S,
    const float* __restrict__ emb,
    const unsigned short* __restrict__ Wt1t, const float* __restrict__ bt1,
    const unsigned short* __restrict__ Wt2t, const float* __restrict__ bt2,
    const unsigned short* __restrict__ We1Ft, const float* __restrict__ be1,
    float* __restrict__ Hh, float* __restrict__ P,
    const float* __restrict__ X, int* __restrict__ idxb,
    const float* __restrict__ We1, const float* __restrict__ We2,
    const float* __restrict__ Wx1, const float* __restrict__ Wh1,
    const float* __restrict__ Wh2, const float* __restrict__ Wd1,
    const float* __restrict__ Wp1, const float* __restrict__ Wr1,
    const float* __restrict__ Wr2,
    unsigned short* __restrict__ WeF,  unsigned short* __restrict__ We2t,
    unsigned short* __restrict__ Wx1t, unsigned short* __restrict__ Wh1t,
    unsigned short* __restrict__ Wh2t, unsigned short* __restrict__ Wd1t,
    unsigned short* __restrict__ Wp1t, unsigned short* __restrict__ Wr1t,
    unsigned short* __restrict__ Wr2t)
{
    __shared__ __align__(16) unsigned char smem[34816];
    const int tid = threadIdx.x;

    if (blockIdx.x >= BN/32 + BN/64) {
        // ================= prep-rest =================
        int i = (blockIdx.x - (BN/32 + BN/64)) * 256 + tid;
        if (i < 16384) {   // folded symmetric radial weights
            const int ch = i >> 7, k = i & 127;
            float v = 0.0f;
            if (k < 105) {
                const int c = PC_tab[k], e = PE_tab[k];
                v = We1[(size_t)(256 + c*14 + e)*128 + ch];
                if (c != e) v += We1[(size_t)(256 + e*14 + c)*128 + ch];
            }
            WeF[i] = f2bf_rne(v);
            return;
        }
        i -= 16384;
        if (i < 16384) { We2t[i] = f2bf_rne(We2[(size_t)(i % 128)*128 + i/128]); return; }
        i -= 16384;
        if (i < 16384) { Wx1t[i] = f2bf_rne(Wx1[(size_t)(i % 128)*128 + i/128]); return; }
        i -= 16384;
        if (i < 32768) { const int c = i/256, k = i%256; Wh1t[i] = f2bf_rne(Wh1[(size_t)k*128 + c]); return; }
        i -= 32768;
        if (i < 16384) { Wh2t[i] = f2bf_rne(Wh2[(size_t)(i % 128)*128 + i/128]); return; }
        i -= 16384;
        if (i < 32768) {
            const int tt = i/128, k = i%128;
            Wd1t[i] = f2bf_rne((tt < 128) ? Wd1[(size_t)k*128 + tt] : Wd1[(size_t)(128 + k)*128 + (tt - 128)]);
            return;
        }
        i -= 32768;
        if (i < 16384) { Wp1t[i] = f2bf_rne(Wp1[(size_t)(i % 128)*128 + i/128]); return; }
        i -= 16384;
        if (i < 16384) { Wr1t[i] = f2bf_rne(Wr1[(size_t)(i % 128)*128 + i/128]); return; }
        i -= 16384;
        if (i < 4096) {
            const int ch = i >> 7, k = i & 127;
            Wr2t[i] = (ch < NCLS) ? f2bf_rne(Wr2[(size_t)k*NCLS + ch]) : (unsigned short)0;
        }
        return;
    }

    if (blockIdx.x < BN/32) {
        // ================= hhP =================
        unsigned short* A0 = (unsigned short*)smem;
        unsigned short* A1 = A0 + 32*140;
        unsigned short* A2 = A1 + 32*140;
        int*            sInt = (int*)(A2 + 32*140);

        const int wv   = tid >> 6, lane = tid & 63;
        const int quad = lane >> 4, r16 = lane & 15;
        const int col  = tid & 127, rh = tid >> 7;
        const int base = blockIdx.x * 32;

        if (tid < 32) sInt[tid] = S[base + tid];

        const float step  = 1.0f / 127.0f;
        const float coeff = -0.5f / (step * step);
        const float off   = step * (float)col;
        #pragma unroll
        for (int rr = 0; rr < 16; ++rr) {
            const int r = rh*16 + rr;
            const float d = t[base + r] - off + 1e-6f;
            A0[r*140 + col] = f2bf(__expf(coeff * d * d));
        }
        __syncthreads();

        // MM_t1
        {
            v8bf a[2][4];
            #pragma unroll
            for (int g = 0; g < 2; ++g)
                #pragma unroll
                for (int ks = 0; ks < 4; ++ks)
                    a[g][ks] = *(const v8bf*)(A0 + (16*g + r16)*140 + ks*32 + quad*8);
            #pragma unroll
            for (int c2 = 0; c2 < 2; ++c2) {
                const int ch = (wv*2 + c2)*16 + r16;
                v4f acc[2] = {(v4f){0,0,0,0}, (v4f){0,0,0,0}};
                #pragma unroll
                for (int ks = 0; ks < 4; ++ks) {
                    const v8bf bb = *(const v8bf*)(Wt1t + (size_t)ch*128 + ks*32 + quad*8);
                    acc[0] = __builtin_amdgcn_mfma_f32_16x16x32_bf16(a[0][ks], bb, acc[0], 0, 0, 0);
                    acc[1] = __builtin_amdgcn_mfma_f32_16x16x32_bf16(a[1][ks], bb, acc[1], 0, 0, 0);
                }
                const float bc = bt1[ch];
                #pragma unroll
                for (int g = 0; g < 2; ++g)
                    #pragma unroll
                    for (int rr = 0; rr < 4; ++rr)
                        A1[(16*g + quad*4 + rr)*140 + ch] = f2bf(fmaxf(acc[g][rr] + bc, 0.0f));
            }
        }
        __syncthreads();

        // MM_t2
        {
            v8bf a[2][4];
            #pragma unroll
            for (int g = 0; g < 2; ++g)
                #pragma unroll
                for (int ks = 0; ks < 4; ++ks)
                    a[g][ks] = *(const v8bf*)(A1 + (16*g + r16)*140 + ks*32 + quad*8);
            #pragma unroll
            for (int c2 = 0; c2 < 2; ++c2) {
                const int ch = (wv*2 + c2)*16 + r16;
                v4f acc[2] = {(v4f){0,0,0,0}, (v4f){0,0,0,0}};
                #pragma unroll
                for (int ks = 0; ks < 4; ++ks) {
                    const v8bf bb = *(const v8bf*)(Wt2t + (size_t)ch*128 + ks*32 + quad*8);
                    acc[0] = __builtin_amdgcn_mfma_f32_16x16x32_bf16(a[0][ks], bb, acc[0], 0, 0, 0);
                    acc[1] = __builtin_amdgcn_mfma_f32_16x16x32_bf16(a[1][ks], bb, acc[1], 0, 0, 0);
                }
                const float bc = bt2[ch];
                #pragma unroll
                for (int g = 0; g < 2; ++g)
                    #pragma unroll
                    for (int rr = 0; rr < 4; ++rr) {
                        const int row = 16*g + quad*4 + rr;
                        const int node = base + row;
                        const float hh = emb[sInt[row]*128 + ch] + acc[g][rr] + bc;
                        Hh[(size_t)node*128 + ch] = hh;
                        A2[row*140 + ch] = f2bf(silu_f(hh));
                    }
            }
        }
        __syncthreads();

        // MM_P
        {
            v8bf a[2][4];
            #pragma unroll
            for (int g = 0; g < 2; ++g)
                #pragma unroll
                for (int ks = 0; ks < 4; ++ks)
                    a[g][ks] = *(const v8bf*)(A2 + (16*g + r16)*140 + ks*32 + quad*8);
            #pragma unroll
            for (int c2 = 0; c2 < 4; ++c2) {
                const int ch = (wv*4 + c2)*16 + r16;
                v4f acc[2] = {(v4f){0,0,0,0}, (v4f){0,0,0,0}};
                #pragma unroll
                for (int ks = 0; ks < 4; ++ks) {
                    const v8bf bb = *(const v8bf*)(We1Ft + (size_t)ch*128 + ks*32 + quad*8);
                    acc[0] = __builtin_amdgcn_mfma_f32_16x16x32_bf16(a[0][ks], bb, acc[0], 0, 0, 0);
                    acc[1] = __builtin_amdgcn_mfma_f32_16x16x32_bf16(a[1][ks], bb, acc[1], 0, 0, 0);
                }
                const float fb = (ch < 128) ? be1[ch] : 0.0f;
                #pragma unroll
                for (int g = 0; g < 2; ++g)
                    #pragma unroll
                    for (int rr = 0; rr < 4; ++rr)
                        P[(size_t)(base + 16*g + quad*4 + rr)*256 + ch] = acc[g][rr] + fb;
            }
        }
        return;
    }

    // ================= knn =================
    {
        float4* Cc   = (float4*)smem;
        float*  dshp = (float*)(smem + 16384);
        int*    ishp = (int*)  (smem + 25600);

        const int kb = blockIdx.x - BN/32;
        const int lane = tid & 63, wv = tid >> 6;
        const int bb = kb >> 4;
        const int n0 = (kb & 15) << 6;
        const float* Xb = X + (size_t)bb * NPT * 42;

        for (int i = tid; i < NPT; i += 256) {
            const float* p = Xb + (size_t)i*42 + 3;
            Cc[i] = make_float4(p[0], p[1], p[2], 0.0f);
        }
        __syncthreads();

        const int n = n0 + lane;
        const float4 c = Cc[n];

        float dist[KNN]; int ind[KNN];
        #pragma unroll
        for (int k = 0; k < KNN; ++k) { dist[k] = 3.0e38f; ind[k] = -1; }

        const int j0 = wv * 256;
        for (int jj = 0; jj < 256; ++jj) {
            const int j = j0 + jj;
            const float4 q = Cc[j];
            const float dx = __fsub_rn(c.x, q.x);
            const float dy = __fsub_rn(c.y, q.y);
            const float dz = __fsub_rn(c.z, q.z);
            float d = __fadd_rn(__fadd_rn(__fmul_rn(dx,dx), __fmul_rn(dy,dy)), __fmul_rn(dz,dz));
            if (j == n) d = __fadd_rn(d, 1e10f);
            if (d < dist[KNN-1]) {
                dist[KNN-1] = d; ind[KNN-1] = j;
                #pragma unroll
                for (int p = KNN-1; p > 0; --p) {
                    if (dist[p] < dist[p-1]) {
                        float td = dist[p]; dist[p] = dist[p-1]; dist[p-1] = td;
                        int   ti = ind[p];  ind[p]  = ind[p-1];  ind[p-1]  = ti;
                    }
                }
            }
        }
        #pragma unroll
        for (int k = 0; k < KNN; ++k) {
            dshp[((wv*64 + lane))*KNN + k] = dist[k];
            ishp[((wv*64 + lane))*KNN + k] = ind[k];
        }
        __syncthreads();

        if (tid < 64) {
            float fd[KNN]; int fi[KNN];
            #pragma unroll
            for (int k = 0; k < KNN; ++k) { fd[k] = 3.0e38f; fi[k] = -1; }
            for (int w = 0; w < 4; ++w)
                #pragma unroll
                for (int k = 0; k < KNN; ++k) {
                    const float d = dshp[(w*64 + tid)*KNN + k];
                    const int   i = ishp[(w*64 + tid)*KNN + k];
                    if (d < fd[KNN-1]) {
                        fd[KNN-1] = d; fi[KNN-1] = i;
                        #pragma unroll
                        for (int p = KNN-1; p > 0; --p) {
                            if (fd[p] < fd[p-1]) {
                                float td = fd[p]; fd[p] = fd[p-1]; fd[p-1] = td;
                                int   ti = fi[p]; fi[p] = fi[p-1]; fi[p-1] = ti;
                            }
                        }
                    }
                }
            const int node = (bb << 10) + n0 + tid;
            #pragma unroll
            for (int k = 0; k < KNN; ++k) idxb[(size_t)node*KNN + k] = fi[k];
        }
    }
}

// ---------------- K4: MFMA edge pipeline, 16 nodes/block (R11 geometry) ----------------
__global__ __launch_bounds__(256) void k_edge(
    const float* __restrict__ X, const int* __restrict__ idxb,
    const float* __restrict__ P,
    const unsigned short* __restrict__ WeF,
    const unsigned short* __restrict__ We2t,
    const unsigned short* __restrict__ Wx1t,
    const float* __restrict__ be2,
    const float* __restrict__ bx1, const float* __restrict__ Wx2,
    const float* __restrict__ bx2,
    float* __restrict__ msum, float* __restrict__ wbuf)
{
    __shared__ unsigned short radF[16*RSTR];
    __shared__ unsigned short silA[16*SSTR];
    __shared__ unsigned short silB[16*SSTR];
    __shared__ __align__(16) float relS[16][57];
    __shared__ float wred[KNN][16][4];
    __shared__ int   jsh[16][KNN];

    const int tid  = threadIdx.x;
    const int wv   = tid >> 6, lane = tid & 63;
    const int quad = lane >> 4, r16 = lane & 15;
    const int node0 = blockIdx.x * 16;
    const int b     = node0 >> 10;
    const int chan0 = (wv*2 + 0)*16 + r16;
    const int chan1 = (wv*2 + 1)*16 + r16;
    const int srow  = tid >> 4, c16 = tid & 15;

    if (tid < 144) jsh[tid/9][tid%9] = idxb[(size_t)(node0 + tid/9)*KNN + tid%9];

    int offCE[7];
    #pragma unroll
    for (int kk = 0; kk < 7; ++kk) {
        const int f = c16 + 16*kk;
        if (f < 105) offCE[kk] = ((int)PC_tab[f]*4) | (((int)PE_tab[f]*4) << 16);
        else         offCE[kk] = 0;
    }
    {
        const int f6 = 96 + c16, f7 = 112 + c16;
        if (f6 >= 105) radF[srow*RSTR + f6] = 0;
        radF[srow*RSTR + f7] = 0;
    }

    float xr[3] = {0,0,0};
    if (c16 < 14) {
        #pragma unroll
        for (int k = 0; k < 3; ++k)
            xr[k] = X[(size_t)(node0 + srow)*42 + c16*3 + k];
    }

    float pn0[4], pn1[4];
    #pragma unroll
    for (int rr = 0; rr < 4; ++rr) {
        pn0[rr] = P[(size_t)(node0 + quad*4 + rr)*256 + chan0];
        pn1[rr] = P[(size_t)(node0 + quad*4 + rr)*256 + chan1];
    }
    const float be2c0 = be2[chan0], be2c1 = be2[chan1];
    const float bxc0  = bx1[chan0], bxc1  = bx1[chan1];
    const float wxc0  = Wx2[chan0], wxc1  = Wx2[chan1];

    v8bf B1[2][4], B2[2][4], B3[2][4];
    #pragma unroll
    for (int c2 = 0; c2 < 2; ++c2) {
        const int ct = wv*2 + c2;
        #pragma unroll
        for (int ks = 0; ks < 4; ++ks) {
            B1[c2][ks] = *(const v8bf*)(WeF  + (size_t)(ct*16 + r16)*128 + ks*32 + quad*8);
            B2[c2][ks] = *(const v8bf*)(We2t + (size_t)(ct*16 + r16)*128 + ks*32 + quad*8);
            B3[c2][ks] = *(const v8bf*)(Wx1t + (size_t)(ct*16 + r16)*128 + ks*32 + quad*8);
        }
    }

    float msA0[4] = {0,0,0,0}, msA1[4] = {0,0,0,0};

    __syncthreads();

    float xj[3] = {0,0,0};
    if (c16 < 14) {
        const int j = jsh[srow][0];
        #pragma unroll
        for (int k = 0; k < 3; ++k)
            xj[k] = X[(size_t)((b << 10) + j)*42 + c16*3 + k];
    }

    for (int t = 0; t < KNN; ++t) {
        if (c16 < 14) {
            #pragma unroll
            for (int k = 0; k < 3; ++k)
                relS[srow][c16*4 + k] = xr[k] - xj[k];
        }
        if (t + 1 < KNN && c16 < 14) {
            const int j = jsh[srow][t+1];
            #pragma unroll
            for (int k = 0; k < 3; ++k)
                xj[k] = X[(size_t)((b << 10) + j)*42 + c16*3 + k];
        }
        float pj0[4], pj1[4];
        #pragma unroll
        for (int rr = 0; rr < 4; ++rr) {
            const int jq = jsh[quad*4 + rr][t];
            const size_t jrow = (size_t)((b << 10) + jq)*256 + 128;
            pj0[rr] = P[jrow + chan0];
            pj1[rr] = P[jrow + chan1];
        }

        {
            const float* rb = relS[srow];
            #pragma unroll
            for (int kk = 0; kk < 7; ++kk) {
                const int f = c16 + 16*kk;
                if (f < 105) {
                    const int oc = offCE[kk] & 0xffff, oe = offCE[kk] >> 16;
                    const float v = (rb[oc]*rb[oe] + rb[oc+1]*rb[oe+1]
                                   + rb[oc+2]*rb[oe+2]) * (1.0f/14.0f);
                    radF[srow*RSTR + f] = f2bf(silu_f(v));
                }
            }
        }
        __syncthreads();   // B

        v4f acc10 = (v4f){0,0,0,0}, acc11 = (v4f){0,0,0,0};
        #pragma unroll
        for (int ks = 0; ks < 4; ++ks) {
            const v8bf a = *(const v8bf*)(radF + r16*RSTR + ks*32 + quad*8);
            acc10 = __builtin_amdgcn_mfma_f32_16x16x32_bf16(a, B1[0][ks], acc10, 0, 0, 0);
            acc11 = __builtin_amdgcn_mfma_f32_16x16x32_bf16(a, B1[1][ks], acc11, 0, 0, 0);
        }
        #pragma unroll
        for (int rr = 0; rr < 4; ++rr) {
            const int rw = quad*4 + rr;
            silA[rw*SSTR + chan0] = f2bf(silu_f(acc10[rr] + pn0[rr] + pj0[rr]));
            silA[rw*SSTR + chan1] = f2bf(silu_f(acc11[rr] + pn1[rr] + pj1[rr]));
        }
        __syncthreads();   // C

        v4f acc20 = (v4f){0,0,0,0}, acc21 = (v4f){0,0,0,0};
        #pragma unroll
        for (int ks = 0; ks < 4; ++ks) {
            const v8bf a = *(const v8bf*)(silA + r16*SSTR + ks*32 + quad*8);
            acc20 = __builtin_amdgcn_mfma_f32_16x16x32_bf16(a, B2[0][ks], acc20, 0, 0, 0);
            acc21 = __builtin_amdgcn_mfma_f32_16x16x32_bf16(a, B2[1][ks], acc21, 0, 0, 0);
        }
        #pragma unroll
        for (int rr = 0; rr < 4; ++rr) {
            const float m0 = acc20[rr] + be2c0;
            const float m1 = acc21[rr] + be2c1;
            msA0[rr] += m0;  msA1[rr] += m1;
            const int rw = quad*4 + rr;
            silB[rw*SSTR + chan0] = f2bf(silu_f(m0));
            silB[rw*SSTR + chan1] = f2bf(silu_f(m1));
        }
        __syncthreads();   // D

        v4f acc30 = (v4f){0,0,0,0}, acc31 = (v4f){0,0,0,0};
        #pragma unroll
        for (int ks = 0; ks < 4; ++ks) {
            const v8bf a = *(const v8bf*)(silB + r16*SSTR + ks*32 + quad*8);
            acc30 = __builtin_amdgcn_mfma_f32_16x16x32_bf16(a, B3[0][ks], acc30, 0, 0, 0);
            acc31 = __builtin_amdgcn_mfma_f32_16x16x32_bf16(a, B3[1][ks], acc31, 0, 0, 0);
        }
        #pragma unroll
        for (int rr = 0; rr < 4; ++rr) {
            float pr = silu_f(acc30[rr] + bxc0) * wxc0
                     + silu_f(acc31[rr] + bxc1) * wxc1;
            pr += __shfl_xor(pr, 1);
            pr += __shfl_xor(pr, 2);
            pr += __shfl_xor(pr, 4);
            pr += __shfl_xor(pr, 8);
            if (r16 == 0) wred[t][quad*4 + rr][wv] = pr;
        }
    }

    #pragma unroll
    for (int rr = 0; rr < 4; ++rr) {
        msum[(size_t)(node0 + quad*4 + rr)*128 + chan0] = msA0[rr];
        msum[(size_t)(node0 + quad*4 + rr)*128 + chan1] = msA1[rr];
    }
    __syncthreads();
    if (tid < 16*KNN) {
        const int tt = tid / 16, rw = tid % 16;
        wbuf[(size_t)(node0 + rw)*KNN + tt] =
            wred[tt][rw][0] + wred[tt][rw][1] + wred[tt][rw][2] + wred[tt][rw][3] + bx2[0];
    }
}

// ---------------- K5: fused node pipeline, all-MFMA, 32 nodes/block ----------------
__global__ __launch_bounds__(256) void k_nodeF(
    const float* __restrict__ X, const float* __restrict__ Hh,
    const float* __restrict__ msum, const int* __restrict__ idxb,
    const float* __restrict__ wbuf,
    const unsigned short* __restrict__ Wh1t, const float* __restrict__ bh1,
    const unsigned short* __restrict__ Wh2t, const float* __restrict__ bh2,
    const unsigned short* __restrict__ Wd1t, const float* __restrict__ bd1,
    const int* __restrict__ S, const float* __restrict__ emb,
    const unsigned short* __restrict__ Wp1t, const float* __restrict__ bp1,
    const unsigned short* __restrict__ Wr1t, const float* __restrict__ br1,
    const unsigned short* __restrict__ Wr2t, const float* __restrict__ br2,
    float* __restrict__ Hn, float* __restrict__ AB,
    float* __restrict__ outL, float* __restrict__ outX)
{
    __shared__ __align__(16) unsigned short A0[32*268];
    __shared__ __align__(16) unsigned short A1[32*140];
    __shared__ __align__(16) unsigned short A2[32*140];
    __shared__ __align__(16) unsigned short A3[32*140];
    __shared__ int sInt[32];

    const int tid  = threadIdx.x;
    const int wv   = tid >> 6, lane = tid & 63;
    const int quad = lane >> 4, r16 = lane & 15;
    const int base = blockIdx.x * 32;

    if (tid < 32) sInt[tid] = S[base + tid];
    for (int r = 0; r < 32; ++r) {
        const int node = base + r;
        const float v = (tid < 128) ? Hh[(size_t)node*128 + tid]
                                    : msum[(size_t)node*128 + (tid - 128)];
        A0[r*268 + tid] = f2bf(silu_f(v));
    }
    __syncthreads();

    // MM1: K=256
    {
        v8bf a[2][8];
        #pragma unroll
        for (int g = 0; g < 2; ++g)
            #pragma unroll
            for (int ks = 0; ks < 8; ++ks)
                a[g][ks] = *(const v8bf*)(A0 + (16*g + r16)*268 + ks*32 + quad*8);
        #pragma unroll
        for (int c2 = 0; c2 < 2; ++c2) {
            const int ch = (wv*2 + c2)*16 + r16;
            v4f acc[2] = {(v4f){0,0,0,0}, (v4f){0,0,0,0}};
            #pragma unroll
            for (int ks = 0; ks < 8; ++ks) {
                const v8bf bb = *(const v8bf*)(Wh1t + (size_t)ch*256 + ks*32 + quad*8);
                acc[0] = __builtin_amdgcn_mfma_f32_16x16x32_bf16(a[0][ks], bb, acc[0], 0, 0, 0);
                acc[1] = __builtin_amdgcn_mfma_f32_16x16x32_bf16(a[1][ks], bb, acc[1], 0, 0, 0);
            }
            const float bc = bh1[ch];
            #pragma unroll
            for (int g = 0; g < 2; ++g)
                #pragma unroll
                for (int rr = 0; rr < 4; ++rr)
                    A1[(16*g + quad*4 + rr)*140 + ch] = f2bf(silu_f(acc[g][rr] + bc));
        }
    }
    __syncthreads();

    // MM2
    {
        v8bf a[2][4];
        #pragma unroll
        for (int g = 0; g < 2; ++g)
            #pragma unroll
            for (int ks = 0; ks < 4; ++ks)
                a[g][ks] = *(const v8bf*)(A1 + (16*g + r16)*140 + ks*32 + quad*8);
        #pragma unroll
        for (int c2 = 0; c2 < 2; ++c2) {
            const int ch = (wv*2 + c2)*16 + r16;
            v4f acc[2] = {(v4f){0,0,0,0}, (v4f){0,0,0,0}};
            #pragma unroll
            for (int ks = 0; ks < 4; ++ks) {
                const v8bf bb = *(const v8bf*)(Wh2t + (size_t)ch*128 + ks*32 + quad*8);
                acc[0] = __builtin_amdgcn_mfma_f32_16x16x32_bf16(a[0][ks], bb, acc[0], 0, 0, 0);
                acc[1] = __builtin_amdgcn_mfma_f32_16x16x32_bf16(a[1][ks], bb, acc[1], 0, 0, 0);
            }
            const float bc = bh2[ch];
            #pragma unroll
            for (int g = 0; g < 2; ++g)
                #pragma unroll
                for (int rr = 0; rr < 4; ++rr) {
                    const int row = 16*g + quad*4 + rr;
                    const int node = base + row;
                    const float hn = Hh[(size_t)node*128 + ch] + acc[g][rr] + bc;
                    Hn[(size_t)node*128 + ch] = hn;
                    A2[row*140 + ch] = f2bf(silu_f(hn));
                }
        }
    }
    __syncthreads();

    // MM3 (AB) + MM4 (gate)
    {
        v8bf a[2][4];
        #pragma unroll
        for (int g = 0; g < 2; ++g)
            #pragma unroll
            for (int ks = 0; ks < 4; ++ks)
                a[g][ks] = *(const v8bf*)(A2 + (16*g + r16)*140 + ks*32 + quad*8);

        #pragma unroll
        for (int c2 = 0; c2 < 4; ++c2) {
            const int ch = (wv*4 + c2)*16 + r16;
            v4f acc[2] = {(v4f){0,0,0,0}, (v4f){0,0,0,0}};
            #pragma unroll
            for (int ks = 0; ks < 4; ++ks) {
                const v8bf bb = *(const v8bf*)(Wd1t + (size_t)ch*128 + ks*32 + quad*8);
                acc[0] = __builtin_amdgcn_mfma_f32_16x16x32_bf16(a[0][ks], bb, acc[0], 0, 0, 0);
                acc[1] = __builtin_amdgcn_mfma_f32_16x16x32_bf16(a[1][ks], bb, acc[1], 0, 0, 0);
            }
            const float fb = (ch < 128) ? bd1[ch] : 0.0f;
            #pragma unroll
            for (int g = 0; g < 2; ++g)
                #pragma unroll
                for (int rr = 0; rr < 4; ++rr)
                    AB[(size_t)(base + 16*g + quad*4 + rr)*256 + ch] = acc[g][rr] + fb;
        }

        #pragma unroll
        for (int c2 = 0; c2 < 2; ++c2) {
            const int ch = (wv*2 + c2)*16 + r16;
            v4f acc[2] = {(v4f){0,0,0,0}, (v4f){0,0,0,0}};
            #pragma unroll
            for (int ks = 0; ks < 4; ++ks) {
                const v8bf bb = *(const v8bf*)(Wp1t + (size_t)ch*128 + ks*32 + quad*8);
                acc[0] = __builtin_amdgcn_mfma_f32_16x16x32_bf16(a[0][ks], bb, acc[0], 0, 0, 0);
                acc[1] = __builtin_amdgcn_mfma_f32_16x16x32_bf16(a[1][ks], bb, acc[1], 0, 0, 0);
            }
            const float bc = bp1[ch];
            #pragma unroll
            for (int g = 0; g < 2; ++g)
                #pragma unroll
                for (int rr = 0; rr < 4; ++rr) {
                    const int row = 16*g + quad*4 + rr;
                    const float gg = sigm_f(acc[g][rr] + bc);
                    const float x = emb[sInt[row]*128 + ch] * gg;
                    A3[row*140 + ch] = f2bf(silu_f(x));
                }
        }
    }
    __syncthreads();

    // MM5
    {
        v8bf a[2][4];
        #pragma unroll
        for (int g = 0; g < 2; ++g)
            #pragma unroll
            for (int ks = 0; ks < 4; ++ks)
                a[g][ks] = *(const v8bf*)(A3 + (16*g + r16)*140 + ks*32 + quad*8);
        #pragma unroll
        for (int c2 = 0; c2 < 2; ++c2) {
            const int ch = (wv*2 + c2)*16 + r16;
            v4f acc[2] = {(v4f){0,0,0,0}, (v4f){0,0,0,0}};
            #pragma unroll
            for (int ks = 0; ks < 4; ++ks) {
                const v8bf bb = *(const v8bf*)(Wr1t + (size_t)ch*128 + ks*32 + quad*8);
                acc[0] = __builtin_amdgcn_mfma_f32_16x16x32_bf16(a[0][ks], bb, acc[0], 0, 0, 0);
                acc[1] = __builtin_amdgcn_mfma_f32_16x16x32_bf16(a[1][ks], bb, acc[1], 0, 0, 0);
            }
            const float bc = br1[ch];
            #pragma unroll
            for (int g = 0; g < 2; ++g)
                #pragma unroll
                for (int rr = 0; rr < 4; ++rr)
                    A1[(16*g + quad*4 + rr)*140 + ch] = f2bf(silu_f(acc[g][rr] + bc));
        }
    }
    __syncthreads();

    // MM6: logits
    {
        const int g = wv >> 1, ct = wv & 1;
        v8bf a[4];
        #pragma unroll
        for (int ks = 0; ks < 4; ++ks)
            a[ks] = *(const v8bf*)(A1 + (16*g + r16)*140 + ks*32 + quad*8);
        v4f acc = (v4f){0,0,0,0};
        #pragma unroll
        for (int ks = 0; ks < 4; ++ks) {
            const v8bf bb = *(const v8bf*)(Wr2t + (size_t)(ct*16 + r16)*128 + ks*32 + quad*8);
            acc = __builtin_amdgcn_mfma_f32_16x16x32_bf16(a[ks], bb, acc, 0, 0, 0);
        }
        const int col = ct*16 + r16;
        if (col < NCLS) {
            const float bc = br2[col];
            #pragma unroll
            for (int rr = 0; rr < 4; ++rr)
                outL[(size_t)(base + 16*g + quad*4 + rr)*NCLS + col] = acc[rr] + bc;
        }
    }

    // X_out tail
    for (int o = tid; o < 32*CC*3; o += 256) {
        const int r = o / (CC*3), q = o % (CC*3);
        const int node = base + r;
        const int bq = node >> 10;
        const int cq = q / 3, dc = q % 3;
        const float xv = X[((size_t)node*CC + cq)*3 + dc];
        float a = 0.0f;
        for (int k = 0; k < KNN; ++k) {
            const int j = idxb[(size_t)node*KNN + k];
            const float xjv = X[(((size_t)(bq << 10) + j)*CC + cq)*3 + dc];
            a += (xv - xjv) * wbuf[(size_t)node*KNN + k];
        }
        outX[(size_t)node*CC*3 + q] = xv + a / 9.0f;
    }
}

// ---------------- K6: pd, 8 nodes/block, all loads hoisted ----------------
__global__ __launch_bounds__(256) void k_pd2(
    const float* __restrict__ AB, const int* __restrict__ idxb,
    const float* __restrict__ Wd2, const float* __restrict__ bd2,
    float* __restrict__ outPd)
{
    const int tid  = threadIdx.x;
    const int lane = tid & 63, wv = tid >> 6;
    const int c0   = lane, c1 = lane + 64;
    const float w0 = Wd2[c0], w1 = Wd2[c1];
    const float b2 = 2.0f * bd2[0];
    const int nodeA = blockIdx.x * 8 + wv*2;

    // all gathers for both nodes issued before any compute
    float An0[2], An1[2], Bn0[2], Bn1[2];
    float Aj0[2][KNN], Aj1[2][KNN], Bj0[2][KNN], Bj1[2][KNN];
    #pragma unroll
    for (int s = 0; s < 2; ++s) {
        const int node = nodeA + s;
        const int b    = node >> 10;
        int jv = 0;
        if (lane < KNN) jv = idxb[(size_t)node*KNN + lane];
        An0[s] = AB[(size_t)node*256 + c0];
        An1[s] = AB[(size_t)node*256 + c1];
        Bn0[s] = AB[(size_t)node*256 + 128 + c0];
        Bn1[s] = AB[(size_t)node*256 + 128 + c1];
        #pragma unroll
        for (int e = 0; e < KNN; ++e) {
            const size_t jn = (size_t)((b << 10) + __shfl(jv, e)) * 256;
            Aj0[s][e] = AB[jn + c0];       Aj1[s][e] = AB[jn + c1];
            Bj0[s][e] = AB[jn + 128 + c0]; Bj1[s][e] = AB[jn + 128 + c1];
        }
    }
    #pragma unroll
    for (int s = 0; s < 2; ++s) {
        const int node = nodeA + s;
        #pragma unroll
        for (int e = 0; e < KNN; ++e) {
            float p = (silu_f(An0[s] + Bj0[s][e]) + silu_f(Aj0[s][e] + Bn0[s])) * w0
                    + (silu_f(An1[s] + Bj1[s][e]) + silu_f(Aj1[s][e] + Bn1[s])) * w1;
            #pragma unroll
            for (int off = 32; off; off >>= 1) p += __shfl_xor(p, off, 64);
            if (lane == 0) outPd[(size_t)node*KNN + e] = p + b2;
        }
    }
}

extern "C" void kernel_launch(void* const* d_in, const int* in_sizes, int n_in,
                              void* d_out, int out_size, void* d_ws, size_t ws_size,
                              hipStream_t stream)
{
    const float* X   = (const float*)d_in[0];
    const int*   S   = (const int*)  d_in[1];
    const float* t   = (const float*)d_in[2];
    const float* emb = (const float*)d_in[3];
    const float* Wt1 = (const float*)d_in[4];
    const float* bt1 = (const float*)d_in[5];
    const float* Wt2 = (const float*)d_in[6];
    const float* bt2 = (const float*)d_in[7];
    const float* We1 = (const float*)d_in[8];
    const float* be1 = (const float*)d_in[9];
    const float* We2 = (const float*)d_in[10];
    const float* be2 = (const float*)d_in[11];
    const float* Wx1 = (const float*)d_in[12];
    const float* bx1 = (const float*)d_in[13];
    const float* Wx2 = (const float*)d_in[14];
    const float* bx2 = (const float*)d_in[15];
    const float* Wh1 = (const float*)d_in[16];
    const float* bh1 = (const float*)d_in[17];
    const float* Wh2 = (const float*)d_in[18];
    const float* bh2 = (const float*)d_in[19];
    const float* Wd1 = (const float*)d_in[20];
    const float* bd1 = (const float*)d_in[21];
    const float* Wd2 = (const float*)d_in[22];
    const float* bd2 = (const float*)d_in[23];
    const float* Wp1 = (const float*)d_in[24];
    const float* bp1 = (const float*)d_in[25];
    const float* Wr1 = (const float*)d_in[26];
    const float* br1 = (const float*)d_in[27];
    const float* Wr2 = (const float*)d_in[28];
    const float* br2 = (const float*)d_in[29];

    float* out   = (float*)d_out;
    float* outL  = out;
    float* outX  = out + (size_t)BN*NCLS;
    float* outPd = outX + (size_t)BN*CC*3;

    unsigned short* WeF   = (unsigned short*)d_ws;   // 16384
    unsigned short* We2t  = WeF   + 16384;
    unsigned short* Wx1t  = We2t  + 16384;
    unsigned short* Wh1t  = Wx1t  + 16384;           // 32768
    unsigned short* Wh2t  = Wh1t  + 32768;
    unsigned short* Wd1t  = Wh2t  + 16384;           // 32768
    unsigned short* Wp1t  = Wd1t  + 32768;
    unsigned short* Wr1t  = Wp1t  + 16384;
    unsigned short* Wt1t  = Wr1t  + 16384;
    unsigned short* Wt2t  = Wt1t  + 16384;
    unsigned short* We1Ft = Wt2t  + 16384;           // 32768
    unsigned short* Wr2t  = We1Ft + 32768;           // 4096
    float* Hh   = (float*)(Wr2t + 4096);
    float* msum = Hh   + (size_t)BN*EDIM;
    float* Hn   = msum + (size_t)BN*HDIM;
    float* wbuf = Hn   + (size_t)BN*EDIM;
    float* P    = wbuf + (size_t)BN*KNN;
    int*   idxb = (int*)(P + (size_t)BN*256);

    k_prep   <<<256,                  256, 0, stream>>>(We1, Wt1, Wt2, Wt1t, Wt2t, We1Ft);
    k_hhPknn <<<BN/32 + BN/64 + 660,  256, 0, stream>>>(t, S, emb, Wt1t, bt1, Wt2t, bt2, We1Ft, be1,
                                                        Hh, P, X, idxb,
                                                        We1, We2, Wx1, Wh1, Wh2, Wd1, Wp1, Wr1, Wr2,
                                                        WeF, We2t, Wx1t, Wh1t, Wh2t, Wd1t, Wp1t, Wr1t, Wr2t);
    k_edge   <<<BN/16,                256, 0, stream>>>(X, idxb, P, WeF, We2t, Wx1t,
                                                        be2, bx1, Wx2, bx2, msum, wbuf);
    k_nodeF  <<<BN/32,                256, 0, stream>>>(X, Hh, msum, idxb, wbuf,
                                                        Wh1t, bh1, Wh2t, bh2, Wd1t, bd1,
                                                        S, emb, Wp1t, bp1, Wr1t, br1, Wr2t, br2,
                                                        Hn, P, outL, outX);
    k_pd2    <<<BN/8,                 256, 0, stream>>>(P, idxb, Wd2, bd2, outPd);
}